// Round 5
// baseline (515.379 us; speedup 1.0000x reference)
//
#include <hip/hip_runtime.h>

#define N_NODES 50000
#define N_EDGES 800000
#define DIM 128
#define NCLS 40
#define N_PAD 50432        // padded node arrays

typedef __bf16 bf16x8_t __attribute__((ext_vector_type(8)));
typedef unsigned short us8_t __attribute__((ext_vector_type(8)));
typedef float f32x4_t __attribute__((ext_vector_type(4)));

static __device__ __forceinline__ float b2f(unsigned short h) {
    unsigned u = ((unsigned)h) << 16;
    return __builtin_bit_cast(float, u);
}
static __device__ __forceinline__ unsigned short f2b(float f) {
    unsigned u = __builtin_bit_cast(unsigned, f);
    u += 0x7FFFu + ((u >> 16) & 1u);   // RNE; values finite O(1)
    return (unsigned short)(u >> 16);
}
// non-temporal helpers (streaming data: don't pollute the 4MB/XCD L2 the gather table lives in)
static __device__ __forceinline__ unsigned ldnt_u32(const unsigned* p) {
    return __builtin_nontemporal_load(p);
}
static __device__ __forceinline__ int ldnt_i32(const int* p) {
    return __builtin_nontemporal_load(p);
}
static __device__ __forceinline__ float ldnt_f32(const float* p) {
    return __builtin_nontemporal_load(p);
}
static __device__ __forceinline__ float2 ldnt_f2(const float* p) {
    unsigned long long v = __builtin_nontemporal_load((const unsigned long long*)p);
    return __builtin_bit_cast(float2, v);
}
static __device__ __forceinline__ f32x4_t ldnt_f4(const float* p) {
    return __builtin_nontemporal_load((const f32x4_t*)p);
}

// ---------------- merged prep: f32->bf16 shadow of h + weight repack + atomic deg ----------------
// blocks [0,3125): to_bf16 of h (3125*256*8 = 6.4M exact)
// blocks [3125,3301): repack w0/w1/w2/wp into MFMA fragment order
// blocks [3301,3501): deg[dst]++ via global atomics (deg pre-zeroed by hipMemsetAsync)
#define PREP_B 3125
#define REPACK_B 176
#define DEG_B 200
__global__ __launch_bounds__(256) void prep(const float* __restrict__ hsrc,
                                            unsigned short* __restrict__ hout,
                                            const float* __restrict__ w0,
                                            const float* __restrict__ w1,
                                            const float* __restrict__ w2,
                                            const float* __restrict__ wp,
                                            unsigned short* __restrict__ f0h,
                                            unsigned short* __restrict__ f0l,
                                            unsigned short* __restrict__ f1h,
                                            unsigned short* __restrict__ f1l,
                                            unsigned short* __restrict__ f2h,
                                            unsigned short* __restrict__ f2l,
                                            unsigned short* __restrict__ fph,
                                            unsigned short* __restrict__ fpl,
                                            const int* __restrict__ edst,
                                            int* __restrict__ deg) {
    if (blockIdx.x < PREP_B) {
        size_t e0 = ((size_t)blockIdx.x * 256 + threadIdx.x) * 8;
        f32x4_t v0 = ldnt_f4(hsrc + e0);
        f32x4_t v1 = ldnt_f4(hsrc + e0 + 4);
        us8_t o;
        #pragma unroll
        for (int j = 0; j < 4; ++j) { o[j] = f2b(v0[j]); o[4 + j] = f2b(v1[j]); }
        *(us8_t*)(hout + e0) = o;
        return;
    }
    if (blockIdx.x >= PREP_B + REPACK_B) {
        // degree count
        int t0 = (blockIdx.x - PREP_B - REPACK_B) * 256 + threadIdx.x;
        for (int e = t0; e < N_EDGES; e += DEG_B * 256)
            atomicAdd(&deg[ldnt_i32(edst + e)], 1);
        return;
    }
    int t = (blockIdx.x - PREP_B) * 256 + threadIdx.x;
    const float* src;
    unsigned short *dh, *dl;
    int idx, ncols;
    if (t < 16384)      { src = w0; dh = f0h; dl = f0l; idx = t;         ncols = 128; }
    else if (t < 32768) { src = w1; dh = f1h; dl = f1l; idx = t - 16384; ncols = 128; }
    else if (t < 38912) { src = w2; dh = f2h; dl = f2l; idx = t - 32768; ncols = 48; }
    else if (t < 45056) { src = wp; dh = fph; dl = fpl; idx = t - 38912; ncols = 48; }
    else return;
    int k = idx / ncols, n = idx - k * ncols;
    float v;
    if (ncols == 128) v = src[k * 128 + n];
    else              v = (n < NCLS) ? src[k * NCLS + n] : 0.f;
    int nt = n >> 4, m = n & 15, kt = k >> 5, quad = (k >> 3) & 3, j = k & 7;
    int off = ((nt * 4 + kt) * 64 + quad * 16 + m) * 8 + j;
    unsigned short hi = f2b(v);
    dh[off] = hi;
    dl[off] = f2b(v - b2f(hi));
}

// ---------------- single-block exclusive scan of deg -> rs, cur, dinv ----------------
// 1024 threads x 49 contiguous elements each (50176 >= 50000).
__global__ __launch_bounds__(1024) void scan50k(const int* __restrict__ deg,
                                                int* __restrict__ rs,
                                                int* __restrict__ cur,
                                                float* __restrict__ dinv) {
    __shared__ int lds[1024];
    const int PER = 49;
    int tid = threadIdx.x;
    int s0 = tid * PER;
    int lsum = 0;
    for (int k = 0; k < PER; ++k) {
        int n = s0 + k;
        lsum += (n < N_NODES) ? deg[n] : 0;
    }
    lds[tid] = lsum;
    __syncthreads();
    #pragma unroll
    for (int off = 1; off < 1024; off <<= 1) {
        int v = lds[tid];
        int add = (tid >= off) ? lds[tid - off] : 0;
        __syncthreads();
        lds[tid] = v + add;
        __syncthreads();
    }
    int run = lds[tid] - lsum;     // exclusive prefix for this thread's range
    for (int k = 0; k < PER; ++k) {
        int n = s0 + k;
        if (n < N_NODES) {
            int d = deg[n];
            rs[n] = run;
            cur[n] = run;
            dinv[n] = (d > 0) ? (1.0f / (float)d) : 0.0f;
            run += d;
        }
    }
}

// ---------------- CSR fill via atomic cursors (order within a list arbitrary; sums tolerant) ----------------
#define FILL_B 800
__global__ __launch_bounds__(256) void fill_atomic(const int* __restrict__ esrc,
                                                   const int* __restrict__ edst,
                                                   const float* __restrict__ mask,
                                                   int* __restrict__ cur,
                                                   unsigned* __restrict__ csr) {
    int t0 = blockIdx.x * 256 + threadIdx.x;
    for (int e = t0; e < N_EDGES; e += FILL_B * 256) {
        int d = ldnt_i32(edst + e);
        int s = ldnt_i32(esrc + e);
        float mk = ldnt_f32(mask + e);
        int slot = atomicAdd(&cur[d], 1);
        csr[slot] = (unsigned)s | ((unsigned)f2b(mk) << 16);   // cached store: read next kernel
    }
}

// ---------------- gather primitives: issue 16 feature loads / accumulate them ----------------
static __device__ __forceinline__ void issue16(const unsigned short* __restrict__ xb,
                                               unsigned pk, int lane, unsigned* vv) {
    #pragma unroll
    for (int j = 0; j < 16; ++j) {
        unsigned p = (unsigned)__builtin_amdgcn_readlane((int)pk, j);  // 0 for j>=nb
        vv[j] = *(const unsigned*)(xb + (size_t)(p & 0xFFFFu) * DIM + lane * 2);
    }
}
static __device__ __forceinline__ void accum16(unsigned pk, const unsigned* vv,
                                               float& acc0, float& acc1) {
    #pragma unroll
    for (int j = 0; j < 16; ++j) {
        unsigned p = (unsigned)__builtin_amdgcn_readlane((int)pk, j);
        float mm = b2f((unsigned short)(p >> 16));                     // 0 for j>=nb
        acc0 += mm * b2f((unsigned short)(vv[j] & 0xFFFFu));
        acc1 += mm * b2f((unsigned short)(vv[j] >> 16));
    }
}

// ---------------- software-pipelined gather of 4 consecutive nodes into LDS ----------------
// XNT: non-temporal residual read (true when the residual row is not reread later).
template<bool XNT>
static __device__ __forceinline__ void gather4(const unsigned short* __restrict__ xb,
                                               const float* __restrict__ xres,
                                               const int* __restrict__ rs,
                                               const int* __restrict__ deg,
                                               const float* __restrict__ dinv,
                                               const unsigned* __restrict__ csr,
                                               int nb0, int lane,
                                               float (*ldsrow)[132], int row0) {
    int rs4[4], dg4[4];
    float di4[4];
    #pragma unroll
    for (int i = 0; i < 4; ++i) {
        int n = nb0 + i;
        rs4[i] = rs[n];
        dg4[i] = deg[n];
        di4[i] = dinv[n];
    }
    unsigned pk0, pk1, pk2, pk3;
    pk0 = (lane < (dg4[0] < 16 ? dg4[0] : 16)) ? ldnt_u32(csr + rs4[0] + lane) : 0u;
    pk1 = (lane < (dg4[1] < 16 ? dg4[1] : 16)) ? ldnt_u32(csr + rs4[1] + lane) : 0u;

    unsigned vvA[16], vvB[16];
    issue16(xb, pk0, lane, vvA);       // node 0 features in flight

    unsigned pkq[4] = {pk0, pk1, 0u, 0u};
    #pragma unroll
    for (int i = 0; i < 4; ++i) {
        if (i == 0) pk2 = (lane < (dg4[2] < 16 ? dg4[2] : 16)) ? ldnt_u32(csr + rs4[2] + lane) : 0u;
        if (i == 1) pk3 = (lane < (dg4[3] < 16 ? dg4[3] : 16)) ? ldnt_u32(csr + rs4[3] + lane) : 0u;
        if (i == 0) pkq[2] = pk2;
        if (i == 1) pkq[3] = pk3;
        if (i < 3) issue16(xb, pkq[i + 1], lane, (i & 1) ? vvA : vvB);  // next node in flight
        float acc0 = 0.f, acc1 = 0.f;
        accum16(pkq[i], (i & 1) ? vvB : vvA, acc0, acc1);
        // extra chunks (deg > 16), serial (rarer path)
        for (int base = 16; base < dg4[i]; base += 16) {
            int nb = dg4[i] - base;
            if (nb > 16) nb = 16;
            unsigned pke = (lane < nb) ? ldnt_u32(csr + rs4[i] + base + lane) : 0u;
            unsigned vvE[16];
            issue16(xb, pke, lane, vvE);
            accum16(pke, vvE, acc0, acc1);
        }
        float di = di4[i];
        float2 xp;
        if constexpr (XNT) xp = ldnt_f2(xres + (size_t)(nb0 + i) * DIM + lane * 2);
        else               xp = *(const float2*)(xres + (size_t)(nb0 + i) * DIM + lane * 2);
        ldsrow[row0 + i][lane * 2]     = xp.x + acc0 * di;
        ldsrow[row0 + i][lane * 2 + 1] = xp.y + acc1 * di;
    }
}

// ---------------- fused agg + GEMM[N,128]x[128,128] + BN + ReLU ----------------
// 16 rows per block, 4 waves x 4 nodes (proven best structure, R2/R3: ~48 us).
__global__ __launch_bounds__(256) void fused_layer(const unsigned short* __restrict__ xb,
                                                   const float* __restrict__ x,
                                                   const int* __restrict__ rs,
                                                   const int* __restrict__ deg,
                                                   const float* __restrict__ dinv,
                                                   const unsigned* __restrict__ csr,
                                                   const unsigned short* __restrict__ wfh,
                                                   const unsigned short* __restrict__ wfl,
                                                   const float* __restrict__ bias,
                                                   const float* __restrict__ gam,
                                                   const float* __restrict__ bet,
                                                   const float* __restrict__ rm,
                                                   const float* __restrict__ rv,
                                                   float* __restrict__ out,
                                                   unsigned short* __restrict__ outb) {
    __shared__ float lds[16][132];   // 8.4 KB
    int tid = threadIdx.x;
    int wave = tid >> 6, lane = tid & 63;
    int rbase = blockIdx.x * 16;     // 3125 * 16 == 50000 exactly

    // ---- phase 1: x residual rows are read exactly once -> non-temporal ----
    gather4<true>(xb, x, rs, deg, dinv, csr, rbase + wave * 4, lane, lds, wave * 4);
    __syncthreads();   // cross-lane LDS dependency: barrier REQUIRED

    // ---- phase 2: 16x128 GEMM, 2 col-tiles per wave ----
    int m = lane & 15, quad = lane >> 4;
    const float* ap = &lds[m][0];

    us8_t ah[4], al[4];
    #pragma unroll
    for (int kt = 0; kt < 4; ++kt) {
        f32x4_t p0 = *(const f32x4_t*)(ap + kt * 32 + quad * 8);
        f32x4_t p1 = *(const f32x4_t*)(ap + kt * 32 + quad * 8 + 4);
        #pragma unroll
        for (int j = 0; j < 4; ++j) {
            unsigned short h0 = f2b(p0[j]);
            unsigned short h1 = f2b(p1[j]);
            ah[kt][j] = h0;
            ah[kt][4 + j] = h1;
            al[kt][j] = f2b(p0[j] - b2f(h0));
            al[kt][4 + j] = f2b(p1[j] - b2f(h1));
        }
    }

    f32x4_t acc[2] = {};
    #pragma unroll
    for (int kt = 0; kt < 4; ++kt) {
        #pragma unroll
        for (int t = 0; t < 2; ++t) {
            int nt = wave * 2 + t;
            int boff = ((nt * 4 + kt) * 64 + lane) * 8;
            us8_t bh = *(const us8_t*)(wfh + boff);
            us8_t bl = *(const us8_t*)(wfl + boff);
            acc[t] = __builtin_amdgcn_mfma_f32_16x16x32_bf16(
                __builtin_bit_cast(bf16x8_t, ah[kt]),
                __builtin_bit_cast(bf16x8_t, bh), acc[t], 0, 0, 0);
            acc[t] = __builtin_amdgcn_mfma_f32_16x16x32_bf16(
                __builtin_bit_cast(bf16x8_t, ah[kt]),
                __builtin_bit_cast(bf16x8_t, bl), acc[t], 0, 0, 0);
            acc[t] = __builtin_amdgcn_mfma_f32_16x16x32_bf16(
                __builtin_bit_cast(bf16x8_t, al[kt]),
                __builtin_bit_cast(bf16x8_t, bh), acc[t], 0, 0, 0);
        }
    }

    #pragma unroll
    for (int t = 0; t < 2; ++t) {
        int nt = wave * 2 + t;
        int j = nt * 16 + m;
        float bj = bias[j];
        float sc = gam[j] * rsqrtf(rv[j] + 1e-5f);
        float sh = bet[j] - rm[j] * sc;
        #pragma unroll
        for (int i = 0; i < 4; ++i) {
            int r = rbase + quad * 4 + i;
            float z = fmaxf((acc[t][i] + bj) * sc + sh, 0.f);
            __builtin_nontemporal_store(z, out + (size_t)r * DIM + j);  // streamed next layer
            outb[(size_t)r * DIM + j] = f2b(z);                         // gathered next layer: keep cached
        }
    }
}

// ---------------- fused final: agg + h3 = relu(BN((h2+agg)@w2+b2)); out = (h2@wp+bp+h3)*0.5 ----------------
// 16 rows per block; waves 0..2 own the 3 col-tiles (both acc2 and accp); wave 3 gathers only.
__global__ __launch_bounds__(256) void fused_final2(const unsigned short* __restrict__ xb,
                                                    const float* __restrict__ h2,
                                                    const int* __restrict__ rs,
                                                    const int* __restrict__ deg,
                                                    const float* __restrict__ dinv,
                                                    const unsigned* __restrict__ csr,
                                                    const unsigned short* __restrict__ f2h,
                                                    const unsigned short* __restrict__ f2l,
                                                    const unsigned short* __restrict__ fph,
                                                    const unsigned short* __restrict__ fpl,
                                                    const float* __restrict__ b2,
                                                    const float* __restrict__ g2,
                                                    const float* __restrict__ be2,
                                                    const float* __restrict__ rm2,
                                                    const float* __restrict__ rv2,
                                                    const float* __restrict__ bp,
                                                    float* __restrict__ out) {
    __shared__ float lds[16][132];
    int tid = threadIdx.x;
    int wave = tid >> 6, lane = tid & 63;
    int rbase = blockIdx.x * 16;

    // ---- phase 1: h2 rows ARE reread below (aph) -> cached residual read ----
    gather4<false>(xb, h2, rs, deg, dinv, csr, rbase + wave * 4, lane, lds, wave * 4);
    __syncthreads();

    if (wave == 3) return;   // waves 0..2 handle the 3 col-tiles

    // ---- phase 2 ----
    int m = lane & 15, quad = lane >> 4;
    int arow = rbase + m;
    const float* ap2 = &lds[m][0];
    const float* aph = h2 + (size_t)arow * DIM;

    us8_t a2h[4], a2l[4], ahh[4], ahl[4];
    #pragma unroll
    for (int kt = 0; kt < 4; ++kt) {
        f32x4_t p0 = *(const f32x4_t*)(ap2 + kt * 32 + quad * 8);
        f32x4_t p1 = *(const f32x4_t*)(ap2 + kt * 32 + quad * 8 + 4);
        f32x4_t q0 = *(const f32x4_t*)(aph + kt * 32 + quad * 8);
        f32x4_t q1 = *(const f32x4_t*)(aph + kt * 32 + quad * 8 + 4);
        #pragma unroll
        for (int j = 0; j < 4; ++j) {
            unsigned short h0 = f2b(p0[j]), h1 = f2b(p1[j]);
            a2h[kt][j] = h0; a2h[kt][4 + j] = h1;
            a2l[kt][j] = f2b(p0[j] - b2f(h0));
            a2l[kt][4 + j] = f2b(p1[j] - b2f(h1));
            unsigned short g0 = f2b(q0[j]), g1 = f2b(q1[j]);
            ahh[kt][j] = g0; ahh[kt][4 + j] = g1;
            ahl[kt][j] = f2b(q0[j] - b2f(g0));
            ahl[kt][4 + j] = f2b(q1[j] - b2f(g1));
        }
    }

    int nt = wave;           // 0..2
    f32x4_t acc2 = {};
    f32x4_t accp = {};
    #pragma unroll
    for (int kt = 0; kt < 4; ++kt) {
        int boff = ((nt * 4 + kt) * 64 + lane) * 8;
        us8_t b2hv = *(const us8_t*)(f2h + boff);
        us8_t b2lv = *(const us8_t*)(f2l + boff);
        us8_t bphv = *(const us8_t*)(fph + boff);
        us8_t bplv = *(const us8_t*)(fpl + boff);
        acc2 = __builtin_amdgcn_mfma_f32_16x16x32_bf16(
            __builtin_bit_cast(bf16x8_t, a2h[kt]),
            __builtin_bit_cast(bf16x8_t, b2hv), acc2, 0, 0, 0);
        acc2 = __builtin_amdgcn_mfma_f32_16x16x32_bf16(
            __builtin_bit_cast(bf16x8_t, a2h[kt]),
            __builtin_bit_cast(bf16x8_t, b2lv), acc2, 0, 0, 0);
        acc2 = __builtin_amdgcn_mfma_f32_16x16x32_bf16(
            __builtin_bit_cast(bf16x8_t, a2l[kt]),
            __builtin_bit_cast(bf16x8_t, b2hv), acc2, 0, 0, 0);
        accp = __builtin_amdgcn_mfma_f32_16x16x32_bf16(
            __builtin_bit_cast(bf16x8_t, ahh[kt]),
            __builtin_bit_cast(bf16x8_t, bphv), accp, 0, 0, 0);
        accp = __builtin_amdgcn_mfma_f32_16x16x32_bf16(
            __builtin_bit_cast(bf16x8_t, ahh[kt]),
            __builtin_bit_cast(bf16x8_t, bplv), accp, 0, 0, 0);
        accp = __builtin_amdgcn_mfma_f32_16x16x32_bf16(
            __builtin_bit_cast(bf16x8_t, ahl[kt]),
            __builtin_bit_cast(bf16x8_t, bphv), accp, 0, 0, 0);
    }

    int j = nt * 16 + m;
    if (j < NCLS) {
        float b2j = b2[j];
        float sc = g2[j] * rsqrtf(rv2[j] + 1e-5f);
        float sh = be2[j] - rm2[j] * sc;
        float bpj = bp[j];
        #pragma unroll
        for (int i = 0; i < 4; ++i) {
            int r = rbase + quad * 4 + i;
            float z = fmaxf((acc2[i] + b2j) * sc + sh, 0.f);
            float p = accp[i] + bpj;
            __builtin_nontemporal_store((p + z) * 0.5f, out + (size_t)r * NCLS + j);
        }
    }
}

extern "C" void kernel_launch(void* const* d_in, const int* in_sizes, int n_in,
                              void* d_out, int out_size, void* d_ws, size_t ws_size,
                              hipStream_t stream) {
    const float* h    = (const float*)d_in[0];
    const int* esrc   = (const int*)d_in[1];
    const int* edst   = (const int*)d_in[2];
    const float* mask = (const float*)d_in[3];
    const float* w0   = (const float*)d_in[4];
    const float* b0   = (const float*)d_in[5];
    const float* g0   = (const float*)d_in[6];
    const float* be0  = (const float*)d_in[7];
    const float* rm0  = (const float*)d_in[8];
    const float* rv0  = (const float*)d_in[9];
    const float* w1   = (const float*)d_in[10];
    const float* b1   = (const float*)d_in[11];
    const float* g1   = (const float*)d_in[12];
    const float* be1  = (const float*)d_in[13];
    const float* rm1  = (const float*)d_in[14];
    const float* rv1  = (const float*)d_in[15];
    const float* w2   = (const float*)d_in[16];
    const float* b2   = (const float*)d_in[17];
    const float* g2   = (const float*)d_in[18];
    const float* be2  = (const float*)d_in[19];
    const float* rm2  = (const float*)d_in[20];
    const float* rv2  = (const float*)d_in[21];
    const float* wp   = (const float*)d_in[22];
    const float* bp   = (const float*)d_in[23];

    char* ws = (char*)d_ws;
    size_t off = 0;
    auto alloc = [&](size_t bytes) {
        char* p = ws + off;
        off = (off + bytes + 255) & ~(size_t)255;
        return p;
    };
    int* rs       = (int*)alloc(N_PAD * 4);
    int* deg      = (int*)alloc(N_PAD * 4);
    int* cur      = (int*)alloc(N_PAD * 4);
    float* dinv   = (float*)alloc(N_PAD * 4);
    unsigned* csr = (unsigned*)alloc((size_t)N_EDGES * 4);
    float* hbA    = (float*)alloc((size_t)N_NODES * DIM * 4);
    float* hbB    = (float*)alloc((size_t)N_NODES * DIM * 4);
    unsigned short* xb16  = (unsigned short*)alloc((size_t)N_NODES * DIM * 2);
    unsigned short* hbA16 = (unsigned short*)alloc((size_t)N_NODES * DIM * 2);
    unsigned short* hbB16 = (unsigned short*)alloc((size_t)N_NODES * DIM * 2);
    unsigned short* f0h = (unsigned short*)alloc(16384 * 2);
    unsigned short* f0l = (unsigned short*)alloc(16384 * 2);
    unsigned short* f1h = (unsigned short*)alloc(16384 * 2);
    unsigned short* f1l = (unsigned short*)alloc(16384 * 2);
    unsigned short* f2h = (unsigned short*)alloc(6144 * 2);
    unsigned short* f2l = (unsigned short*)alloc(6144 * 2);
    unsigned short* fph = (unsigned short*)alloc(6144 * 2);
    unsigned short* fpl = (unsigned short*)alloc(6144 * 2);

    const int GB16 = N_NODES / 16;   // 3125, exact

    hipMemsetAsync(deg, 0, N_NODES * 4, stream);
    prep<<<PREP_B + REPACK_B + DEG_B, 256, 0, stream>>>(
        h, xb16, w0, w1, w2, wp,
        f0h, f0l, f1h, f1l, f2h, f2l, fph, fpl, edst, deg);
    scan50k<<<1, 1024, 0, stream>>>(deg, rs, cur, dinv);
    fill_atomic<<<FILL_B, 256, 0, stream>>>(esrc, edst, mask, cur, csr);

    // layer 0: reads (h, xb16) -> writes (hbA, hbA16)
    fused_layer<<<GB16, 256, 0, stream>>>(xb16, h, rs, deg, dinv, csr,
                                          f0h, f0l, b0, g0, be0, rm0, rv0, hbA, hbA16);
    // layer 1: reads (hbA, hbA16) -> writes (hbB, hbB16)  (double-buffered)
    fused_layer<<<GB16, 256, 0, stream>>>(hbA16, hbA, rs, deg, dinv, csr,
                                          f1h, f1l, b1, g1, be1, rm1, rv1, hbB, hbB16);
    // layer 2 + predict, fused: reads (hbB, hbB16) -> d_out
    fused_final2<<<GB16, 256, 0, stream>>>(hbB16, hbB, rs, deg, dinv, csr,
                                           f2h, f2l, fph, fpl,
                                           b2, g2, be2, rm2, rv2, bp, (float*)d_out);
}

// Round 6
// 345.394 us; speedup vs baseline: 1.4921x; 1.4921x over previous
//
#include <hip/hip_runtime.h>

#define N_NODES 50000
#define N_EDGES 800000
#define DIM 128
#define NCLS 40
#define N_PAD 50432        // 197*256, padded node arrays
#define NPB 197            // node-scan blocks (197*256 = 50432 >= 50000)

typedef __bf16 bf16x8_t __attribute__((ext_vector_type(8)));
typedef unsigned short us8_t __attribute__((ext_vector_type(8)));
typedef float f32x4_t __attribute__((ext_vector_type(4)));

static __device__ __forceinline__ float b2f(unsigned short h) {
    unsigned u = ((unsigned)h) << 16;
    return __builtin_bit_cast(float, u);
}
static __device__ __forceinline__ unsigned short f2b(float f) {
    unsigned u = __builtin_bit_cast(unsigned, f);
    u += 0x7FFFu + ((u >> 16) & 1u);   // RNE; values finite O(1)
    return (unsigned short)(u >> 16);
}

// ---------------- merged prep: f32->bf16 shadow of h + weight repack + atomic deg ----------------
// blocks [0,3125): to_bf16 of h (3125*256*8 = 6.4M exact)
// blocks [3125,3301): repack w0/w1/w2/wp into MFMA fragment order
// blocks [3301,3501): deg[dst]++ via global atomics (deg pre-zeroed by hipMemsetAsync)
#define PREP_B 3125
#define REPACK_B 176
#define DEG_B 200
__global__ __launch_bounds__(256) void prep(const float* __restrict__ hsrc,
                                            unsigned short* __restrict__ hout,
                                            const float* __restrict__ w0,
                                            const float* __restrict__ w1,
                                            const float* __restrict__ w2,
                                            const float* __restrict__ wp,
                                            unsigned short* __restrict__ f0h,
                                            unsigned short* __restrict__ f0l,
                                            unsigned short* __restrict__ f1h,
                                            unsigned short* __restrict__ f1l,
                                            unsigned short* __restrict__ f2h,
                                            unsigned short* __restrict__ f2l,
                                            unsigned short* __restrict__ fph,
                                            unsigned short* __restrict__ fpl,
                                            const int* __restrict__ edst,
                                            int* __restrict__ deg) {
    if (blockIdx.x < PREP_B) {
        size_t e0 = ((size_t)blockIdx.x * 256 + threadIdx.x) * 8;
        f32x4_t v0 = *(const f32x4_t*)(hsrc + e0);
        f32x4_t v1 = *(const f32x4_t*)(hsrc + e0 + 4);
        us8_t o;
        #pragma unroll
        for (int j = 0; j < 4; ++j) { o[j] = f2b(v0[j]); o[4 + j] = f2b(v1[j]); }
        *(us8_t*)(hout + e0) = o;
        return;
    }
    if (blockIdx.x >= PREP_B + REPACK_B) {
        // degree count
        int t0 = (blockIdx.x - PREP_B - REPACK_B) * 256 + threadIdx.x;
        for (int e = t0; e < N_EDGES; e += DEG_B * 256)
            atomicAdd(&deg[edst[e]], 1);
        return;
    }
    int t = (blockIdx.x - PREP_B) * 256 + threadIdx.x;
    const float* src;
    unsigned short *dh, *dl;
    int idx, ncols;
    if (t < 16384)      { src = w0; dh = f0h; dl = f0l; idx = t;         ncols = 128; }
    else if (t < 32768) { src = w1; dh = f1h; dl = f1l; idx = t - 16384; ncols = 128; }
    else if (t < 38912) { src = w2; dh = f2h; dl = f2l; idx = t - 32768; ncols = 48; }
    else if (t < 45056) { src = wp; dh = fph; dl = fpl; idx = t - 38912; ncols = 48; }
    else return;
    int k = idx / ncols, n = idx - k * ncols;
    float v;
    if (ncols == 128) v = src[k * 128 + n];
    else              v = (n < NCLS) ? src[k * NCLS + n] : 0.f;
    int nt = n >> 4, m = n & 15, kt = k >> 5, quad = (k >> 3) & 3, j = k & 7;
    int off = ((nt * 4 + kt) * 64 + quad * 16 + m) * 8 + j;
    unsigned short hi = f2b(v);
    dh[off] = hi;
    dl[off] = f2b(v - b2f(hi));
}

// ---------------- hierarchical scan of deg: partial sums then offsets ----------------
__global__ __launch_bounds__(256) void deg_partial(const int* __restrict__ deg,
                                                   int* __restrict__ partial) {
    __shared__ int lds[256];
    int n = blockIdx.x * 256 + threadIdx.x;
    lds[threadIdx.x] = (n < N_NODES) ? deg[n] : 0;
    __syncthreads();
    #pragma unroll
    for (int off = 128; off > 0; off >>= 1) {
        if (threadIdx.x < off) lds[threadIdx.x] += lds[threadIdx.x + off];
        __syncthreads();
    }
    if (threadIdx.x == 0) partial[blockIdx.x] = lds[0];
}

__global__ __launch_bounds__(256) void deg_scan(const int* __restrict__ deg,
                                                const int* __restrict__ partial,
                                                int* __restrict__ rs,
                                                int* __restrict__ cur,
                                                float* __restrict__ dinv) {
    __shared__ int lds[256];
    int b = blockIdx.x, tid = threadIdx.x;
    // block offset = sum of partial[j], j < b  (b < NPB <= 256)
    lds[tid] = (tid < b) ? partial[tid] : 0;
    __syncthreads();
    #pragma unroll
    for (int off = 128; off > 0; off >>= 1) {
        if (tid < off) lds[tid] += lds[tid + off];
        __syncthreads();
    }
    int boff = lds[0];
    __syncthreads();
    int n = b * 256 + tid;
    int d = (n < N_NODES) ? deg[n] : 0;
    lds[tid] = d;
    __syncthreads();
    #pragma unroll
    for (int off = 1; off < 256; off <<= 1) {
        int v = lds[tid];
        int add = (tid >= off) ? lds[tid - off] : 0;
        __syncthreads();
        lds[tid] = v + add;
        __syncthreads();
    }
    if (n < N_NODES) {
        int excl = boff + lds[tid] - d;
        rs[n] = excl;
        cur[n] = excl;
        dinv[n] = (d > 0) ? (1.0f / (float)d) : 0.0f;
    }
}

// ---------------- CSR fill via atomic cursors (order within a list arbitrary; sums tolerant) ----------------
__global__ __launch_bounds__(256) void fill_atomic(const int* __restrict__ esrc,
                                                   const int* __restrict__ edst,
                                                   const float* __restrict__ mask,
                                                   int* __restrict__ cur,
                                                   unsigned* __restrict__ csr) {
    int e = blockIdx.x * 256 + threadIdx.x;
    if (e >= N_EDGES) return;
    int d = edst[e];
    int s = esrc[e];
    float mk = mask[e];
    int slot = atomicAdd(&cur[d], 1);
    csr[slot] = (unsigned)s | ((unsigned)f2b(mk) << 16);
}

// ---------------- gather primitives: issue 16 feature loads / accumulate them ----------------
static __device__ __forceinline__ void issue16(const unsigned short* __restrict__ xb,
                                               unsigned pk, int lane, unsigned* vv) {
    #pragma unroll
    for (int j = 0; j < 16; ++j) {
        unsigned p = (unsigned)__builtin_amdgcn_readlane((int)pk, j);  // 0 for j>=nb
        vv[j] = *(const unsigned*)(xb + (size_t)(p & 0xFFFFu) * DIM + lane * 2);
    }
}
static __device__ __forceinline__ void accum16(unsigned pk, const unsigned* vv,
                                               float& acc0, float& acc1) {
    #pragma unroll
    for (int j = 0; j < 16; ++j) {
        unsigned p = (unsigned)__builtin_amdgcn_readlane((int)pk, j);
        float mm = b2f((unsigned short)(p >> 16));                     // 0 for j>=nb
        acc0 += mm * b2f((unsigned short)(vv[j] & 0xFFFFu));
        acc1 += mm * b2f((unsigned short)(vv[j] >> 16));
    }
}

// ---------------- software-pipelined gather of 4 consecutive nodes into LDS ----------------
// Lane owns dims lane*2, lane*2+1. csr chunks prefetched 2 nodes ahead; feature
// loads issued 1 node ahead (ping-pong vvA/vvB) so node i's accumulate VALU
// overlaps node i+1's 16 in-flight L2-miss loads.  (R3-proven, no nt.)
static __device__ __forceinline__ void gather4(const unsigned short* __restrict__ xb,
                                               const float* __restrict__ xres,
                                               const int* __restrict__ rs,
                                               const int* __restrict__ deg,
                                               const float* __restrict__ dinv,
                                               const unsigned* __restrict__ csr,
                                               int nb0, int lane,
                                               float (*ldsrow)[132], int row0) {
    int rs4[4], dg4[4];
    float di4[4];
    #pragma unroll
    for (int i = 0; i < 4; ++i) {
        int n = nb0 + i;
        rs4[i] = rs[n];
        dg4[i] = deg[n];
        di4[i] = dinv[n];
    }
    unsigned pk0, pk1, pk2, pk3;
    pk0 = (lane < (dg4[0] < 16 ? dg4[0] : 16)) ? csr[rs4[0] + lane] : 0u;
    pk1 = (lane < (dg4[1] < 16 ? dg4[1] : 16)) ? csr[rs4[1] + lane] : 0u;

    unsigned vvA[16], vvB[16];
    issue16(xb, pk0, lane, vvA);       // node 0 features in flight

    unsigned pkq[4] = {pk0, pk1, 0u, 0u};
    #pragma unroll
    for (int i = 0; i < 4; ++i) {
        if (i == 0) pk2 = (lane < (dg4[2] < 16 ? dg4[2] : 16)) ? csr[rs4[2] + lane] : 0u;
        if (i == 1) pk3 = (lane < (dg4[3] < 16 ? dg4[3] : 16)) ? csr[rs4[3] + lane] : 0u;
        if (i == 0) pkq[2] = pk2;
        if (i == 1) pkq[3] = pk3;
        if (i < 3) issue16(xb, pkq[i + 1], lane, (i & 1) ? vvA : vvB);  // next node in flight
        float acc0 = 0.f, acc1 = 0.f;
        accum16(pkq[i], (i & 1) ? vvB : vvA, acc0, acc1);
        // extra chunks (deg > 16), serial (rarer path)
        for (int base = 16; base < dg4[i]; base += 16) {
            int nb = dg4[i] - base;
            if (nb > 16) nb = 16;
            unsigned pke = (lane < nb) ? csr[rs4[i] + base + lane] : 0u;
            unsigned vvE[16];
            issue16(xb, pke, lane, vvE);
            accum16(pke, vvE, acc0, acc1);
        }
        float di = di4[i];
        float2 xp = *(const float2*)(xres + (size_t)(nb0 + i) * DIM + lane * 2);
        ldsrow[row0 + i][lane * 2]     = xp.x + acc0 * di;
        ldsrow[row0 + i][lane * 2 + 1] = xp.y + acc1 * di;
    }
}

// ---------------- fused agg + GEMM[N,128]x[128,128] + BN + ReLU ----------------
// 16 rows per block, 4 waves x 4 nodes (proven best structure, R3: ~48.7 us).
__global__ __launch_bounds__(256) void fused_layer(const unsigned short* __restrict__ xb,
                                                   const float* __restrict__ x,
                                                   const int* __restrict__ rs,
                                                   const int* __restrict__ deg,
                                                   const float* __restrict__ dinv,
                                                   const unsigned* __restrict__ csr,
                                                   const unsigned short* __restrict__ wfh,
                                                   const unsigned short* __restrict__ wfl,
                                                   const float* __restrict__ bias,
                                                   const float* __restrict__ gam,
                                                   const float* __restrict__ bet,
                                                   const float* __restrict__ rm,
                                                   const float* __restrict__ rv,
                                                   float* __restrict__ out,
                                                   unsigned short* __restrict__ outb) {
    __shared__ float lds[16][132];   // 8.4 KB
    int tid = threadIdx.x;
    int wave = tid >> 6, lane = tid & 63;
    int rbase = blockIdx.x * 16;     // 3125 * 16 == 50000 exactly

    // ---- phase 1 ----
    gather4(xb, x, rs, deg, dinv, csr, rbase + wave * 4, lane, lds, wave * 4);
    __syncthreads();   // cross-lane LDS dependency: barrier REQUIRED

    // ---- phase 2: 16x128 GEMM, 2 col-tiles per wave ----
    int m = lane & 15, quad = lane >> 4;
    const float* ap = &lds[m][0];

    us8_t ah[4], al[4];
    #pragma unroll
    for (int kt = 0; kt < 4; ++kt) {
        f32x4_t p0 = *(const f32x4_t*)(ap + kt * 32 + quad * 8);
        f32x4_t p1 = *(const f32x4_t*)(ap + kt * 32 + quad * 8 + 4);
        #pragma unroll
        for (int j = 0; j < 4; ++j) {
            unsigned short h0 = f2b(p0[j]);
            unsigned short h1 = f2b(p1[j]);
            ah[kt][j] = h0;
            ah[kt][4 + j] = h1;
            al[kt][j] = f2b(p0[j] - b2f(h0));
            al[kt][4 + j] = f2b(p1[j] - b2f(h1));
        }
    }

    f32x4_t acc[2] = {};
    #pragma unroll
    for (int kt = 0; kt < 4; ++kt) {
        #pragma unroll
        for (int t = 0; t < 2; ++t) {
            int nt = wave * 2 + t;
            int boff = ((nt * 4 + kt) * 64 + lane) * 8;
            us8_t bh = *(const us8_t*)(wfh + boff);
            us8_t bl = *(const us8_t*)(wfl + boff);
            acc[t] = __builtin_amdgcn_mfma_f32_16x16x32_bf16(
                __builtin_bit_cast(bf16x8_t, ah[kt]),
                __builtin_bit_cast(bf16x8_t, bh), acc[t], 0, 0, 0);
            acc[t] = __builtin_amdgcn_mfma_f32_16x16x32_bf16(
                __builtin_bit_cast(bf16x8_t, ah[kt]),
                __builtin_bit_cast(bf16x8_t, bl), acc[t], 0, 0, 0);
            acc[t] = __builtin_amdgcn_mfma_f32_16x16x32_bf16(
                __builtin_bit_cast(bf16x8_t, al[kt]),
                __builtin_bit_cast(bf16x8_t, bh), acc[t], 0, 0, 0);
        }
    }

    #pragma unroll
    for (int t = 0; t < 2; ++t) {
        int nt = wave * 2 + t;
        int j = nt * 16 + m;
        float bj = bias[j];
        float sc = gam[j] * rsqrtf(rv[j] + 1e-5f);
        float sh = bet[j] - rm[j] * sc;
        #pragma unroll
        for (int i = 0; i < 4; ++i) {
            int r = rbase + quad * 4 + i;
            float z = fmaxf((acc[t][i] + bj) * sc + sh, 0.f);
            out[(size_t)r * DIM + j] = z;
            outb[(size_t)r * DIM + j] = f2b(z);
        }
    }
}

// ---------------- fused final: agg + h3 = relu(BN((h2+agg)@w2+b2)); out = (h2@wp+bp+h3)*0.5 ----------------
// 16 rows per block; waves 0..2 own the 3 col-tiles (both acc2 and accp); wave 3 gathers only.
__global__ __launch_bounds__(256) void fused_final2(const unsigned short* __restrict__ xb,
                                                    const float* __restrict__ h2,
                                                    const int* __restrict__ rs,
                                                    const int* __restrict__ deg,
                                                    const float* __restrict__ dinv,
                                                    const unsigned* __restrict__ csr,
                                                    const unsigned short* __restrict__ f2h,
                                                    const unsigned short* __restrict__ f2l,
                                                    const unsigned short* __restrict__ fph,
                                                    const unsigned short* __restrict__ fpl,
                                                    const float* __restrict__ b2,
                                                    const float* __restrict__ g2,
                                                    const float* __restrict__ be2,
                                                    const float* __restrict__ rm2,
                                                    const float* __restrict__ rv2,
                                                    const float* __restrict__ bp,
                                                    float* __restrict__ out) {
    __shared__ float lds[16][132];
    int tid = threadIdx.x;
    int wave = tid >> 6, lane = tid & 63;
    int rbase = blockIdx.x * 16;

    // ---- phase 1: aggregate (h2 + agg) rows into LDS ----
    gather4(xb, h2, rs, deg, dinv, csr, rbase + wave * 4, lane, lds, wave * 4);
    __syncthreads();

    if (wave == 3) return;   // waves 0..2 handle the 3 col-tiles

    // ---- phase 2 ----
    int m = lane & 15, quad = lane >> 4;
    int arow = rbase + m;
    const float* ap2 = &lds[m][0];
    const float* aph = h2 + (size_t)arow * DIM;

    us8_t a2h[4], a2l[4], ahh[4], ahl[4];
    #pragma unroll
    for (int kt = 0; kt < 4; ++kt) {
        f32x4_t p0 = *(const f32x4_t*)(ap2 + kt * 32 + quad * 8);
        f32x4_t p1 = *(const f32x4_t*)(ap2 + kt * 32 + quad * 8 + 4);
        f32x4_t q0 = *(const f32x4_t*)(aph + kt * 32 + quad * 8);
        f32x4_t q1 = *(const f32x4_t*)(aph + kt * 32 + quad * 8 + 4);
        #pragma unroll
        for (int j = 0; j < 4; ++j) {
            unsigned short h0 = f2b(p0[j]), h1 = f2b(p1[j]);
            a2h[kt][j] = h0; a2h[kt][4 + j] = h1;
            a2l[kt][j] = f2b(p0[j] - b2f(h0));
            a2l[kt][4 + j] = f2b(p1[j] - b2f(h1));
            unsigned short g0 = f2b(q0[j]), g1 = f2b(q1[j]);
            ahh[kt][j] = g0; ahh[kt][4 + j] = g1;
            ahl[kt][j] = f2b(q0[j] - b2f(g0));
            ahl[kt][4 + j] = f2b(q1[j] - b2f(g1));
        }
    }

    int nt = wave;           // 0..2
    f32x4_t acc2 = {};
    f32x4_t accp = {};
    #pragma unroll
    for (int kt = 0; kt < 4; ++kt) {
        int boff = ((nt * 4 + kt) * 64 + lane) * 8;
        us8_t b2hv = *(const us8_t*)(f2h + boff);
        us8_t b2lv = *(const us8_t*)(f2l + boff);
        us8_t bphv = *(const us8_t*)(fph + boff);
        us8_t bplv = *(const us8_t*)(fpl + boff);
        acc2 = __builtin_amdgcn_mfma_f32_16x16x32_bf16(
            __builtin_bit_cast(bf16x8_t, a2h[kt]),
            __builtin_bit_cast(bf16x8_t, b2hv), acc2, 0, 0, 0);
        acc2 = __builtin_amdgcn_mfma_f32_16x16x32_bf16(
            __builtin_bit_cast(bf16x8_t, a2h[kt]),
            __builtin_bit_cast(bf16x8_t, b2lv), acc2, 0, 0, 0);
        acc2 = __builtin_amdgcn_mfma_f32_16x16x32_bf16(
            __builtin_bit_cast(bf16x8_t, a2l[kt]),
            __builtin_bit_cast(bf16x8_t, b2hv), acc2, 0, 0, 0);
        accp = __builtin_amdgcn_mfma_f32_16x16x32_bf16(
            __builtin_bit_cast(bf16x8_t, ahh[kt]),
            __builtin_bit_cast(bf16x8_t, bphv), accp, 0, 0, 0);
        accp = __builtin_amdgcn_mfma_f32_16x16x32_bf16(
            __builtin_bit_cast(bf16x8_t, ahh[kt]),
            __builtin_bit_cast(bf16x8_t, bplv), accp, 0, 0, 0);
        accp = __builtin_amdgcn_mfma_f32_16x16x32_bf16(
            __builtin_bit_cast(bf16x8_t, ahl[kt]),
            __builtin_bit_cast(bf16x8_t, bphv), accp, 0, 0, 0);
    }

    int j = nt * 16 + m;
    if (j < NCLS) {
        float b2j = b2[j];
        float sc = g2[j] * rsqrtf(rv2[j] + 1e-5f);
        float sh = be2[j] - rm2[j] * sc;
        float bpj = bp[j];
        #pragma unroll
        for (int i = 0; i < 4; ++i) {
            int r = rbase + quad * 4 + i;
            float z = fmaxf((acc2[i] + b2j) * sc + sh, 0.f);
            float p = accp[i] + bpj;
            out[(size_t)r * NCLS + j] = (p + z) * 0.5f;
        }
    }
}

extern "C" void kernel_launch(void* const* d_in, const int* in_sizes, int n_in,
                              void* d_out, int out_size, void* d_ws, size_t ws_size,
                              hipStream_t stream) {
    const float* h    = (const float*)d_in[0];
    const int* esrc   = (const int*)d_in[1];
    const int* edst   = (const int*)d_in[2];
    const float* mask = (const float*)d_in[3];
    const float* w0   = (const float*)d_in[4];
    const float* b0   = (const float*)d_in[5];
    const float* g0   = (const float*)d_in[6];
    const float* be0  = (const float*)d_in[7];
    const float* rm0  = (const float*)d_in[8];
    const float* rv0  = (const float*)d_in[9];
    const float* w1   = (const float*)d_in[10];
    const float* b1   = (const float*)d_in[11];
    const float* g1   = (const float*)d_in[12];
    const float* be1  = (const float*)d_in[13];
    const float* rm1  = (const float*)d_in[14];
    const float* rv1  = (const float*)d_in[15];
    const float* w2   = (const float*)d_in[16];
    const float* b2   = (const float*)d_in[17];
    const float* g2   = (const float*)d_in[18];
    const float* be2  = (const float*)d_in[19];
    const float* rm2  = (const float*)d_in[20];
    const float* rv2  = (const float*)d_in[21];
    const float* wp   = (const float*)d_in[22];
    const float* bp   = (const float*)d_in[23];

    char* ws = (char*)d_ws;
    size_t off = 0;
    auto alloc = [&](size_t bytes) {
        char* p = ws + off;
        off = (off + bytes + 255) & ~(size_t)255;
        return p;
    };
    int* rs       = (int*)alloc(N_PAD * 4);
    int* deg      = (int*)alloc(N_PAD * 4);
    int* cur      = (int*)alloc(N_PAD * 4);
    float* dinv   = (float*)alloc(N_PAD * 4);
    int* partial  = (int*)alloc(256 * 4);
    unsigned* csr = (unsigned*)alloc((size_t)N_EDGES * 4);
    float* hbA    = (float*)alloc((size_t)N_NODES * DIM * 4);
    float* hbB    = (float*)alloc((size_t)N_NODES * DIM * 4);
    unsigned short* xb16  = (unsigned short*)alloc((size_t)N_NODES * DIM * 2);
    unsigned short* hbA16 = (unsigned short*)alloc((size_t)N_NODES * DIM * 2);
    unsigned short* hbB16 = (unsigned short*)alloc((size_t)N_NODES * DIM * 2);
    unsigned short* f0h = (unsigned short*)alloc(16384 * 2);
    unsigned short* f0l = (unsigned short*)alloc(16384 * 2);
    unsigned short* f1h = (unsigned short*)alloc(16384 * 2);
    unsigned short* f1l = (unsigned short*)alloc(16384 * 2);
    unsigned short* f2h = (unsigned short*)alloc(6144 * 2);
    unsigned short* f2l = (unsigned short*)alloc(6144 * 2);
    unsigned short* fph = (unsigned short*)alloc(6144 * 2);
    unsigned short* fpl = (unsigned short*)alloc(6144 * 2);

    const int GB16 = N_NODES / 16;   // 3125, exact

    hipMemsetAsync(deg, 0, N_NODES * 4, stream);
    prep<<<PREP_B + REPACK_B + DEG_B, 256, 0, stream>>>(
        h, xb16, w0, w1, w2, wp,
        f0h, f0l, f1h, f1l, f2h, f2l, fph, fpl, edst, deg);
    deg_partial<<<NPB, 256, 0, stream>>>(deg, partial);
    deg_scan<<<NPB, 256, 0, stream>>>(deg, partial, rs, cur, dinv);
    fill_atomic<<<(N_EDGES + 255) / 256, 256, 0, stream>>>(esrc, edst, mask, cur, csr);

    // layer 0: reads (h, xb16) -> writes (hbA, hbA16)
    fused_layer<<<GB16, 256, 0, stream>>>(xb16, h, rs, deg, dinv, csr,
                                          f0h, f0l, b0, g0, be0, rm0, rv0, hbA, hbA16);
    // layer 1: reads (hbA, hbA16) -> writes (hbB, hbB16)  (double-buffered)
    fused_layer<<<GB16, 256, 0, stream>>>(hbA16, hbA, rs, deg, dinv, csr,
                                          f1h, f1l, b1, g1, be1, rm1, rv1, hbB, hbB16);
    // layer 2 + predict, fused: reads (hbB, hbB16) -> d_out
    fused_final2<<<GB16, 256, 0, stream>>>(hbB16, hbB, rs, deg, dinv, csr,
                                           f2h, f2l, fph, fpl,
                                           b2, g2, be2, rm2, rv2, bp, (float*)d_out);
}

// Round 7
// 331.193 us; speedup vs baseline: 1.5561x; 1.0429x over previous
//
#include <hip/hip_runtime.h>

#define N_NODES 50000
#define N_EDGES 800000
#define DIM 128
#define NCLS 40
#define N_PAD 50432        // 197*256, padded node arrays
#define NPB 197            // node-scan blocks (197*256 = 50432 >= 50000)

typedef __bf16 bf16x8_t __attribute__((ext_vector_type(8)));
typedef unsigned short us8_t __attribute__((ext_vector_type(8)));
typedef float f32x4_t __attribute__((ext_vector_type(4)));

static __device__ __forceinline__ float b2f(unsigned short h) {
    unsigned u = ((unsigned)h) << 16;
    return __builtin_bit_cast(float, u);
}
static __device__ __forceinline__ unsigned short f2b(float f) {
    unsigned u = __builtin_bit_cast(unsigned, f);
    u += 0x7FFFu + ((u >> 16) & 1u);   // RNE; values finite O(1)
    return (unsigned short)(u >> 16);
}

// ---------------- merged prep: f32->bf16 shadow of h + weight repack + deg count ----------------
// blocks [0,3125): to_bf16 of h (3125*256*8 = 6.4M exact)
// blocks [3125,3301): repack w0/w1/w2/wp into MFMA fragment order
// blocks [3301,6426): deg[dst]++ -- ONE edge per thread, ONE atomic, no serial loop
//                     (R6 lesson: 200 blocks x 16 serialized atomics = 45 us tail)
#define PREP_B 3125
#define REPACK_B 176
#define DEGC_B 3125        // 3125*256 == 800000 exactly
__global__ __launch_bounds__(256) void prep(const float* __restrict__ hsrc,
                                            unsigned short* __restrict__ hout,
                                            const float* __restrict__ w0,
                                            const float* __restrict__ w1,
                                            const float* __restrict__ w2,
                                            const float* __restrict__ wp,
                                            unsigned short* __restrict__ f0h,
                                            unsigned short* __restrict__ f0l,
                                            unsigned short* __restrict__ f1h,
                                            unsigned short* __restrict__ f1l,
                                            unsigned short* __restrict__ f2h,
                                            unsigned short* __restrict__ f2l,
                                            unsigned short* __restrict__ fph,
                                            unsigned short* __restrict__ fpl,
                                            const int* __restrict__ edst,
                                            int* __restrict__ deg) {
    if (blockIdx.x < PREP_B) {
        size_t e0 = ((size_t)blockIdx.x * 256 + threadIdx.x) * 8;
        f32x4_t v0 = *(const f32x4_t*)(hsrc + e0);
        f32x4_t v1 = *(const f32x4_t*)(hsrc + e0 + 4);
        us8_t o;
        #pragma unroll
        for (int j = 0; j < 4; ++j) { o[j] = f2b(v0[j]); o[4 + j] = f2b(v1[j]); }
        *(us8_t*)(hout + e0) = o;
        return;
    }
    if (blockIdx.x >= PREP_B + REPACK_B) {
        int e = (blockIdx.x - PREP_B - REPACK_B) * 256 + threadIdx.x;  // < 800000 exact
        atomicAdd(&deg[edst[e]], 1);
        return;
    }
    int t = (blockIdx.x - PREP_B) * 256 + threadIdx.x;
    const float* src;
    unsigned short *dh, *dl;
    int idx, ncols;
    if (t < 16384)      { src = w0; dh = f0h; dl = f0l; idx = t;         ncols = 128; }
    else if (t < 32768) { src = w1; dh = f1h; dl = f1l; idx = t - 16384; ncols = 128; }
    else if (t < 38912) { src = w2; dh = f2h; dl = f2l; idx = t - 32768; ncols = 48; }
    else if (t < 45056) { src = wp; dh = fph; dl = fpl; idx = t - 38912; ncols = 48; }
    else return;
    int k = idx / ncols, n = idx - k * ncols;
    float v;
    if (ncols == 128) v = src[k * 128 + n];
    else              v = (n < NCLS) ? src[k * NCLS + n] : 0.f;
    int nt = n >> 4, m = n & 15, kt = k >> 5, quad = (k >> 3) & 3, j = k & 7;
    int off = ((nt * 4 + kt) * 64 + quad * 16 + m) * 8 + j;
    unsigned short hi = f2b(v);
    dh[off] = hi;
    dl[off] = f2b(v - b2f(hi));
}

// ---------------- hierarchical scan of deg: partial sums then offsets ----------------
__global__ __launch_bounds__(256) void deg_partial(const int* __restrict__ deg,
                                                   int* __restrict__ partial) {
    __shared__ int lds[256];
    int n = blockIdx.x * 256 + threadIdx.x;
    lds[threadIdx.x] = (n < N_NODES) ? deg[n] : 0;
    __syncthreads();
    #pragma unroll
    for (int off = 128; off > 0; off >>= 1) {
        if (threadIdx.x < off) lds[threadIdx.x] += lds[threadIdx.x + off];
        __syncthreads();
    }
    if (threadIdx.x == 0) partial[blockIdx.x] = lds[0];
}

__global__ __launch_bounds__(256) void deg_scan(const int* __restrict__ deg,
                                                const int* __restrict__ partial,
                                                int* __restrict__ rs,
                                                int* __restrict__ cur,
                                                float* __restrict__ dinv) {
    __shared__ int lds[256];
    int b = blockIdx.x, tid = threadIdx.x;
    lds[tid] = (tid < b) ? partial[tid] : 0;
    __syncthreads();
    #pragma unroll
    for (int off = 128; off > 0; off >>= 1) {
        if (tid < off) lds[tid] += lds[tid + off];
        __syncthreads();
    }
    int boff = lds[0];
    __syncthreads();
    int n = b * 256 + tid;
    int d = (n < N_NODES) ? deg[n] : 0;
    lds[tid] = d;
    __syncthreads();
    #pragma unroll
    for (int off = 1; off < 256; off <<= 1) {
        int v = lds[tid];
        int add = (tid >= off) ? lds[tid - off] : 0;
        __syncthreads();
        lds[tid] = v + add;
        __syncthreads();
    }
    if (n < N_NODES) {
        int excl = boff + lds[tid] - d;
        rs[n] = excl;
        cur[n] = excl;
        dinv[n] = (d > 0) ? (1.0f / (float)d) : 0.0f;
    }
}

// ---------------- CSR fill via atomic cursors (order within a list arbitrary; sums tolerant) ----------------
__global__ __launch_bounds__(256) void fill_atomic(const int* __restrict__ esrc,
                                                   const int* __restrict__ edst,
                                                   const float* __restrict__ mask,
                                                   int* __restrict__ cur,
                                                   unsigned* __restrict__ csr) {
    int e = blockIdx.x * 256 + threadIdx.x;
    if (e >= N_EDGES) return;
    int d = edst[e];
    int s = esrc[e];
    float mk = mask[e];
    int slot = atomicAdd(&cur[d], 1);
    csr[slot] = (unsigned)s | ((unsigned)f2b(mk) << 16);
}

// ---------------- gather primitives: issue 16 feature loads / accumulate them ----------------
static __device__ __forceinline__ void issue16(const unsigned short* __restrict__ xb,
                                               unsigned pk, int lane, unsigned* vv) {
    #pragma unroll
    for (int j = 0; j < 16; ++j) {
        unsigned p = (unsigned)__builtin_amdgcn_readlane((int)pk, j);  // 0 for j>=nb
        vv[j] = *(const unsigned*)(xb + (size_t)(p & 0xFFFFu) * DIM + lane * 2);
    }
}
static __device__ __forceinline__ void accum16(unsigned pk, const unsigned* vv,
                                               float& acc0, float& acc1) {
    #pragma unroll
    for (int j = 0; j < 16; ++j) {
        unsigned p = (unsigned)__builtin_amdgcn_readlane((int)pk, j);
        float mm = b2f((unsigned short)(p >> 16));                     // 0 for j>=nb
        acc0 += mm * b2f((unsigned short)(vv[j] & 0xFFFFu));
        acc1 += mm * b2f((unsigned short)(vv[j] >> 16));
    }
}

// ---------------- software-pipelined gather of 4 consecutive nodes into LDS ----------------
// RES32: residual from f32 array (layer 0 reads input h). Otherwise residual is
// reconstructed from the hi+lo bf16 tables (hi read L2-warms the gather table;
// reconstruction error 2^-18 relative -- ulp-level).
template<bool RES32>
static __device__ __forceinline__ void gather4(const unsigned short* __restrict__ xb,
                                               const float* __restrict__ xres,
                                               const unsigned short* __restrict__ xlo,
                                               const int* __restrict__ rs,
                                               const int* __restrict__ deg,
                                               const float* __restrict__ dinv,
                                               const unsigned* __restrict__ csr,
                                               int nb0, int lane,
                                               float (*ldsrow)[132], int row0) {
    int rs4[4], dg4[4];
    float di4[4];
    #pragma unroll
    for (int i = 0; i < 4; ++i) {
        int n = nb0 + i;
        rs4[i] = rs[n];
        dg4[i] = deg[n];
        di4[i] = dinv[n];
    }
    unsigned pk0, pk1, pk2, pk3;
    pk0 = (lane < (dg4[0] < 16 ? dg4[0] : 16)) ? csr[rs4[0] + lane] : 0u;
    pk1 = (lane < (dg4[1] < 16 ? dg4[1] : 16)) ? csr[rs4[1] + lane] : 0u;

    unsigned vvA[16], vvB[16];
    issue16(xb, pk0, lane, vvA);       // node 0 features in flight

    unsigned pkq[4] = {pk0, pk1, 0u, 0u};
    #pragma unroll
    for (int i = 0; i < 4; ++i) {
        if (i == 0) pk2 = (lane < (dg4[2] < 16 ? dg4[2] : 16)) ? csr[rs4[2] + lane] : 0u;
        if (i == 1) pk3 = (lane < (dg4[3] < 16 ? dg4[3] : 16)) ? csr[rs4[3] + lane] : 0u;
        if (i == 0) pkq[2] = pk2;
        if (i == 1) pkq[3] = pk3;
        if (i < 3) issue16(xb, pkq[i + 1], lane, (i & 1) ? vvA : vvB);  // next node in flight
        float acc0 = 0.f, acc1 = 0.f;
        accum16(pkq[i], (i & 1) ? vvB : vvA, acc0, acc1);
        // extra chunks (deg > 16), serial (rarer path)
        for (int base = 16; base < dg4[i]; base += 16) {
            int nb = dg4[i] - base;
            if (nb > 16) nb = 16;
            unsigned pke = (lane < nb) ? csr[rs4[i] + base + lane] : 0u;
            unsigned vvE[16];
            issue16(xb, pke, lane, vvE);
            accum16(pke, vvE, acc0, acc1);
        }
        float di = di4[i];
        float x0, x1;
        if constexpr (RES32) {
            float2 xp = *(const float2*)(xres + (size_t)(nb0 + i) * DIM + lane * 2);
            x0 = xp.x; x1 = xp.y;
        } else {
            unsigned hv = *(const unsigned*)(xb  + (size_t)(nb0 + i) * DIM + lane * 2);
            unsigned lv = *(const unsigned*)(xlo + (size_t)(nb0 + i) * DIM + lane * 2);
            x0 = b2f((unsigned short)(hv & 0xFFFFu)) + b2f((unsigned short)(lv & 0xFFFFu));
            x1 = b2f((unsigned short)(hv >> 16))     + b2f((unsigned short)(lv >> 16));
        }
        ldsrow[row0 + i][lane * 2]     = x0 + acc0 * di;
        ldsrow[row0 + i][lane * 2 + 1] = x1 + acc1 * di;
    }
}

// ---------------- fused agg + GEMM[N,128]x[128,128] + BN + ReLU ----------------
// 16 rows per block, 4 waves x 4 nodes (proven structure, ~48.7 us).
// Output stored as hi+lo bf16 tables (4 B/elem vs old 6 B/elem f32+bf16).
template<bool RES32>
__global__ __launch_bounds__(256) void fused_layer(const unsigned short* __restrict__ xb,
                                                   const float* __restrict__ xres,
                                                   const unsigned short* __restrict__ xlo,
                                                   const int* __restrict__ rs,
                                                   const int* __restrict__ deg,
                                                   const float* __restrict__ dinv,
                                                   const unsigned* __restrict__ csr,
                                                   const unsigned short* __restrict__ wfh,
                                                   const unsigned short* __restrict__ wfl,
                                                   const float* __restrict__ bias,
                                                   const float* __restrict__ gam,
                                                   const float* __restrict__ bet,
                                                   const float* __restrict__ rm,
                                                   const float* __restrict__ rv,
                                                   unsigned short* __restrict__ outhi,
                                                   unsigned short* __restrict__ outlo) {
    __shared__ float lds[16][132];   // 8.4 KB
    int tid = threadIdx.x;
    int wave = tid >> 6, lane = tid & 63;
    int rbase = blockIdx.x * 16;     // 3125 * 16 == 50000 exactly

    // ---- phase 1 ----
    gather4<RES32>(xb, xres, xlo, rs, deg, dinv, csr, rbase + wave * 4, lane, lds, wave * 4);
    __syncthreads();   // cross-lane LDS dependency: barrier REQUIRED

    // ---- phase 2: 16x128 GEMM, 2 col-tiles per wave ----
    int m = lane & 15, quad = lane >> 4;
    const float* ap = &lds[m][0];

    us8_t ah[4], al[4];
    #pragma unroll
    for (int kt = 0; kt < 4; ++kt) {
        f32x4_t p0 = *(const f32x4_t*)(ap + kt * 32 + quad * 8);
        f32x4_t p1 = *(const f32x4_t*)(ap + kt * 32 + quad * 8 + 4);
        #pragma unroll
        for (int j = 0; j < 4; ++j) {
            unsigned short h0 = f2b(p0[j]);
            unsigned short h1 = f2b(p1[j]);
            ah[kt][j] = h0;
            ah[kt][4 + j] = h1;
            al[kt][j] = f2b(p0[j] - b2f(h0));
            al[kt][4 + j] = f2b(p1[j] - b2f(h1));
        }
    }

    f32x4_t acc[2] = {};
    #pragma unroll
    for (int kt = 0; kt < 4; ++kt) {
        #pragma unroll
        for (int t = 0; t < 2; ++t) {
            int nt = wave * 2 + t;
            int boff = ((nt * 4 + kt) * 64 + lane) * 8;
            us8_t bh = *(const us8_t*)(wfh + boff);
            us8_t bl = *(const us8_t*)(wfl + boff);
            acc[t] = __builtin_amdgcn_mfma_f32_16x16x32_bf16(
                __builtin_bit_cast(bf16x8_t, ah[kt]),
                __builtin_bit_cast(bf16x8_t, bh), acc[t], 0, 0, 0);
            acc[t] = __builtin_amdgcn_mfma_f32_16x16x32_bf16(
                __builtin_bit_cast(bf16x8_t, ah[kt]),
                __builtin_bit_cast(bf16x8_t, bl), acc[t], 0, 0, 0);
            acc[t] = __builtin_amdgcn_mfma_f32_16x16x32_bf16(
                __builtin_bit_cast(bf16x8_t, al[kt]),
                __builtin_bit_cast(bf16x8_t, bh), acc[t], 0, 0, 0);
        }
    }

    #pragma unroll
    for (int t = 0; t < 2; ++t) {
        int nt = wave * 2 + t;
        int j = nt * 16 + m;
        float bj = bias[j];
        float sc = gam[j] * rsqrtf(rv[j] + 1e-5f);
        float sh = bet[j] - rm[j] * sc;
        #pragma unroll
        for (int i = 0; i < 4; ++i) {
            int r = rbase + quad * 4 + i;
            float z = fmaxf((acc[t][i] + bj) * sc + sh, 0.f);
            unsigned short zh = f2b(z);
            outhi[(size_t)r * DIM + j] = zh;
            outlo[(size_t)r * DIM + j] = f2b(z - b2f(zh));
        }
    }
}

// ---------------- fused final: agg + h3 = relu(BN((h2+agg)@w2+b2)); out = (h2@wp+bp+h3)*0.5 ----------------
// h2 arrives as hi+lo tables: predict-path A-fragments load DIRECTLY as us8
// (stored lo == old on-the-fly split, bit-identical GEMM numerics).
__global__ __launch_bounds__(256) void fused_final2(const unsigned short* __restrict__ xb,
                                                    const unsigned short* __restrict__ xlo,
                                                    const int* __restrict__ rs,
                                                    const int* __restrict__ deg,
                                                    const float* __restrict__ dinv,
                                                    const unsigned* __restrict__ csr,
                                                    const unsigned short* __restrict__ f2h,
                                                    const unsigned short* __restrict__ f2l,
                                                    const unsigned short* __restrict__ fph,
                                                    const unsigned short* __restrict__ fpl,
                                                    const float* __restrict__ b2,
                                                    const float* __restrict__ g2,
                                                    const float* __restrict__ be2,
                                                    const float* __restrict__ rm2,
                                                    const float* __restrict__ rv2,
                                                    const float* __restrict__ bp,
                                                    float* __restrict__ out) {
    __shared__ float lds[16][132];
    int tid = threadIdx.x;
    int wave = tid >> 6, lane = tid & 63;
    int rbase = blockIdx.x * 16;

    // ---- phase 1: aggregate (h2 + agg) rows into LDS ----
    gather4<false>(xb, nullptr, xlo, rs, deg, dinv, csr, rbase + wave * 4, lane, lds, wave * 4);
    __syncthreads();

    if (wave == 3) return;   // waves 0..2 handle the 3 col-tiles

    // ---- phase 2 ----
    int m = lane & 15, quad = lane >> 4;
    int arow = rbase + m;
    const float* ap2 = &lds[m][0];
    const unsigned short* aphh = xb  + (size_t)arow * DIM;
    const unsigned short* aphl = xlo + (size_t)arow * DIM;

    us8_t a2h[4], a2l[4], ahh[4], ahl[4];
    #pragma unroll
    for (int kt = 0; kt < 4; ++kt) {
        f32x4_t p0 = *(const f32x4_t*)(ap2 + kt * 32 + quad * 8);
        f32x4_t p1 = *(const f32x4_t*)(ap2 + kt * 32 + quad * 8 + 4);
        ahh[kt] = *(const us8_t*)(aphh + kt * 32 + quad * 8);   // direct hi fragment
        ahl[kt] = *(const us8_t*)(aphl + kt * 32 + quad * 8);   // direct lo fragment
        #pragma unroll
        for (int j = 0; j < 4; ++j) {
            unsigned short h0 = f2b(p0[j]), h1 = f2b(p1[j]);
            a2h[kt][j] = h0; a2h[kt][4 + j] = h1;
            a2l[kt][j] = f2b(p0[j] - b2f(h0));
            a2l[kt][4 + j] = f2b(p1[j] - b2f(h1));
        }
    }

    int nt = wave;           // 0..2
    f32x4_t acc2 = {};
    f32x4_t accp = {};
    #pragma unroll
    for (int kt = 0; kt < 4; ++kt) {
        int boff = ((nt * 4 + kt) * 64 + lane) * 8;
        us8_t b2hv = *(const us8_t*)(f2h + boff);
        us8_t b2lv = *(const us8_t*)(f2l + boff);
        us8_t bphv = *(const us8_t*)(fph + boff);
        us8_t bplv = *(const us8_t*)(fpl + boff);
        acc2 = __builtin_amdgcn_mfma_f32_16x16x32_bf16(
            __builtin_bit_cast(bf16x8_t, a2h[kt]),
            __builtin_bit_cast(bf16x8_t, b2hv), acc2, 0, 0, 0);
        acc2 = __builtin_amdgcn_mfma_f32_16x16x32_bf16(
            __builtin_bit_cast(bf16x8_t, a2h[kt]),
            __builtin_bit_cast(bf16x8_t, b2lv), acc2, 0, 0, 0);
        acc2 = __builtin_amdgcn_mfma_f32_16x16x32_bf16(
            __builtin_bit_cast(bf16x8_t, a2l[kt]),
            __builtin_bit_cast(bf16x8_t, b2hv), acc2, 0, 0, 0);
        accp = __builtin_amdgcn_mfma_f32_16x16x32_bf16(
            __builtin_bit_cast(bf16x8_t, ahh[kt]),
            __builtin_bit_cast(bf16x8_t, bphv), accp, 0, 0, 0);
        accp = __builtin_amdgcn_mfma_f32_16x16x32_bf16(
            __builtin_bit_cast(bf16x8_t, ahh[kt]),
            __builtin_bit_cast(bf16x8_t, bplv), accp, 0, 0, 0);
        accp = __builtin_amdgcn_mfma_f32_16x16x32_bf16(
            __builtin_bit_cast(bf16x8_t, ahl[kt]),
            __builtin_bit_cast(bf16x8_t, bphv), accp, 0, 0, 0);
    }

    int j = nt * 16 + m;
    if (j < NCLS) {
        float b2j = b2[j];
        float sc = g2[j] * rsqrtf(rv2[j] + 1e-5f);
        float sh = be2[j] - rm2[j] * sc;
        float bpj = bp[j];
        #pragma unroll
        for (int i = 0; i < 4; ++i) {
            int r = rbase + quad * 4 + i;
            float z = fmaxf((acc2[i] + b2j) * sc + sh, 0.f);
            float p = accp[i] + bpj;
            out[(size_t)r * NCLS + j] = (p + z) * 0.5f;
        }
    }
}

extern "C" void kernel_launch(void* const* d_in, const int* in_sizes, int n_in,
                              void* d_out, int out_size, void* d_ws, size_t ws_size,
                              hipStream_t stream) {
    const float* h    = (const float*)d_in[0];
    const int* esrc   = (const int*)d_in[1];
    const int* edst   = (const int*)d_in[2];
    const float* mask = (const float*)d_in[3];
    const float* w0   = (const float*)d_in[4];
    const float* b0   = (const float*)d_in[5];
    const float* g0   = (const float*)d_in[6];
    const float* be0  = (const float*)d_in[7];
    const float* rm0  = (const float*)d_in[8];
    const float* rv0  = (const float*)d_in[9];
    const float* w1   = (const float*)d_in[10];
    const float* b1   = (const float*)d_in[11];
    const float* g1   = (const float*)d_in[12];
    const float* be1  = (const float*)d_in[13];
    const float* rm1  = (const float*)d_in[14];
    const float* rv1  = (const float*)d_in[15];
    const float* w2   = (const float*)d_in[16];
    const float* b2   = (const float*)d_in[17];
    const float* g2   = (const float*)d_in[18];
    const float* be2  = (const float*)d_in[19];
    const float* rm2  = (const float*)d_in[20];
    const float* rv2  = (const float*)d_in[21];
    const float* wp   = (const float*)d_in[22];
    const float* bp   = (const float*)d_in[23];

    char* ws = (char*)d_ws;
    size_t off = 0;
    auto alloc = [&](size_t bytes) {
        char* p = ws + off;
        off = (off + bytes + 255) & ~(size_t)255;
        return p;
    };
    int* rs       = (int*)alloc(N_PAD * 4);
    int* deg      = (int*)alloc(N_PAD * 4);
    int* cur      = (int*)alloc(N_PAD * 4);
    float* dinv   = (float*)alloc(N_PAD * 4);
    int* partial  = (int*)alloc(256 * 4);
    unsigned* csr = (unsigned*)alloc((size_t)N_EDGES * 4);
    unsigned short* xb16   = (unsigned short*)alloc((size_t)N_NODES * DIM * 2);
    unsigned short* hbA_hi = (unsigned short*)alloc((size_t)N_NODES * DIM * 2);
    unsigned short* hbA_lo = (unsigned short*)alloc((size_t)N_NODES * DIM * 2);
    unsigned short* hbB_hi = (unsigned short*)alloc((size_t)N_NODES * DIM * 2);
    unsigned short* hbB_lo = (unsigned short*)alloc((size_t)N_NODES * DIM * 2);
    unsigned short* f0h = (unsigned short*)alloc(16384 * 2);
    unsigned short* f0l = (unsigned short*)alloc(16384 * 2);
    unsigned short* f1h = (unsigned short*)alloc(16384 * 2);
    unsigned short* f1l = (unsigned short*)alloc(16384 * 2);
    unsigned short* f2h = (unsigned short*)alloc(6144 * 2);
    unsigned short* f2l = (unsigned short*)alloc(6144 * 2);
    unsigned short* fph = (unsigned short*)alloc(6144 * 2);
    unsigned short* fpl = (unsigned short*)alloc(6144 * 2);

    const int GB16 = N_NODES / 16;   // 3125, exact

    hipMemsetAsync(deg, 0, N_NODES * 4, stream);
    prep<<<PREP_B + REPACK_B + DEGC_B, 256, 0, stream>>>(
        h, xb16, w0, w1, w2, wp,
        f0h, f0l, f1h, f1l, f2h, f2l, fph, fpl, edst, deg);
    deg_partial<<<NPB, 256, 0, stream>>>(deg, partial);
    deg_scan<<<NPB, 256, 0, stream>>>(deg, partial, rs, cur, dinv);
    fill_atomic<<<(N_EDGES + 255) / 256, 256, 0, stream>>>(esrc, edst, mask, cur, csr);

    // layer 0: residual from f32 input h; gather from xb16 -> hbA hi/lo
    fused_layer<true><<<GB16, 256, 0, stream>>>(xb16, h, xb16, rs, deg, dinv, csr,
                                                f0h, f0l, b0, g0, be0, rm0, rv0,
                                                hbA_hi, hbA_lo);
    // layer 1: residual + gather from hbA hi/lo -> hbB hi/lo (double-buffered)
    fused_layer<false><<<GB16, 256, 0, stream>>>(hbA_hi, h, hbA_lo, rs, deg, dinv, csr,
                                                 f1h, f1l, b1, g1, be1, rm1, rv1,
                                                 hbB_hi, hbB_lo);
    // layer 2 + predict, fused: hbB hi/lo -> d_out
    fused_final2<<<GB16, 256, 0, stream>>>(hbB_hi, hbB_lo, rs, deg, dinv, csr,
                                           f2h, f2l, fph, fpl,
                                           b2, g2, be2, rm2, rv2, bp, (float*)d_out);
}

// Round 8
// 296.452 us; speedup vs baseline: 1.7385x; 1.1172x over previous
//
#include <hip/hip_runtime.h>

#define N_NODES 50000
#define N_EDGES 800000
#define DIM 128
#define NCLS 40

// chunked CSR build (R3-proven)
#define NCHUNK 128
#define CE 6250            // NCHUNK*CE == N_EDGES exactly
#define HALF_N 25088       // nodes per half (2*WHALF)
#define WHALF 12544        // packed u32 words per half (= 49*256)
#define SCAN_B 98          // cscan/scan_final blocks (2 halves * 49)
#define N_PAD 50432        // >= 2*HALF_N padded node arrays

typedef __bf16 bf16x8_t __attribute__((ext_vector_type(8)));
typedef unsigned short us8_t __attribute__((ext_vector_type(8)));
typedef float f32x4_t __attribute__((ext_vector_type(4)));

static __device__ __forceinline__ float b2f(unsigned short h) {
    unsigned u = ((unsigned)h) << 16;
    return __builtin_bit_cast(float, u);
}
static __device__ __forceinline__ unsigned short f2b(float f) {
    unsigned u = __builtin_bit_cast(unsigned, f);
    u += 0x7FFFu + ((u >> 16) & 1u);   // RNE; values finite O(1)
    return (unsigned short)(u >> 16);
}

// ---------------- merged prep: f32->bf16 shadow of h + weight repack ----------------
// blocks [0,3125): to_bf16 of h (3125*256*8 = 6.4M exact)
// blocks [3125,3301): repack w0/w1/w2/wp into MFMA fragment order
#define PREP_B 3125
#define REPACK_B 176
__global__ __launch_bounds__(256) void prep(const float* __restrict__ hsrc,
                                            unsigned short* __restrict__ hout,
                                            const float* __restrict__ w0,
                                            const float* __restrict__ w1,
                                            const float* __restrict__ w2,
                                            const float* __restrict__ wp,
                                            unsigned short* __restrict__ f0h,
                                            unsigned short* __restrict__ f0l,
                                            unsigned short* __restrict__ f1h,
                                            unsigned short* __restrict__ f1l,
                                            unsigned short* __restrict__ f2h,
                                            unsigned short* __restrict__ f2l,
                                            unsigned short* __restrict__ fph,
                                            unsigned short* __restrict__ fpl) {
    if (blockIdx.x < PREP_B) {
        size_t e0 = ((size_t)blockIdx.x * 256 + threadIdx.x) * 8;
        f32x4_t v0 = *(const f32x4_t*)(hsrc + e0);
        f32x4_t v1 = *(const f32x4_t*)(hsrc + e0 + 4);
        us8_t o;
        #pragma unroll
        for (int j = 0; j < 4; ++j) { o[j] = f2b(v0[j]); o[4 + j] = f2b(v1[j]); }
        *(us8_t*)(hout + e0) = o;
        return;
    }
    int t = (blockIdx.x - PREP_B) * 256 + threadIdx.x;
    const float* src;
    unsigned short *dh, *dl;
    int idx, ncols;
    if (t < 16384)      { src = w0; dh = f0h; dl = f0l; idx = t;         ncols = 128; }
    else if (t < 32768) { src = w1; dh = f1h; dl = f1l; idx = t - 16384; ncols = 128; }
    else if (t < 38912) { src = w2; dh = f2h; dl = f2l; idx = t - 32768; ncols = 48; }
    else if (t < 45056) { src = wp; dh = fph; dl = fpl; idx = t - 38912; ncols = 48; }
    else return;
    int k = idx / ncols, n = idx - k * ncols;
    float v;
    if (ncols == 128) v = src[k * 128 + n];
    else              v = (n < NCLS) ? src[k * NCLS + n] : 0.f;
    int nt = n >> 4, m = n & 15, kt = k >> 5, quad = (k >> 3) & 3, j = k & 7;
    int off = ((nt * 4 + kt) * 64 + quad * 16 + m) * 8 + j;
    unsigned short hi = f2b(v);
    dh[off] = hi;
    dl[off] = f2b(v - b2f(hi));
}

// ---------------- per-chunk per-node edge counts (LDS atomics); blockIdx.y = half ----------------
__global__ __launch_bounds__(256) void chunk_count(const int* __restrict__ dst,
                                                   unsigned* __restrict__ cnt) {
    __shared__ unsigned lds[WHALF];   // 50 KB
    int c = blockIdx.x, h = blockIdx.y, tid = threadIdx.x;
    for (int w = tid; w < WHALF; w += 256) lds[w] = 0;
    __syncthreads();
    int base = c * CE;
    for (int k = tid; k < CE; k += 256) {
        int local = dst[base + k] - h * HALF_N;
        if (local >= 0 && local < HALF_N)
            atomicAdd(&lds[local >> 1], 1u << ((local & 1) * 16));
    }
    __syncthreads();
    unsigned* out = cnt + ((size_t)(h * NCHUNK + c)) * WHALF;
    for (int w = tid; w < WHALF; w += 256) out[w] = lds[w];
}

// ---------------- scan over chunk axis ----------------
__global__ __launch_bounds__(256) void cscan(unsigned* __restrict__ cnt,
                                             unsigned* __restrict__ degp,
                                             int* __restrict__ partial) {
    __shared__ int lds[256];
    int b = blockIdx.x;
    int h = b / 49;
    int w = (b % 49) * 256 + threadIdx.x;
    unsigned acc = 0;
    for (int c = 0; c < NCHUNK; ++c) {
        size_t idx = ((size_t)(h * NCHUNK + c)) * WHALF + w;
        unsigned v = cnt[idx];
        cnt[idx] = acc;          // exclusive prefix (packed halves)
        acc += v;
    }
    degp[h * WHALF + w] = acc;
    lds[threadIdx.x] = (int)(acc & 0xFFFFu) + (int)(acc >> 16);
    __syncthreads();
    #pragma unroll
    for (int off = 128; off > 0; off >>= 1) {
        if (threadIdx.x < off) lds[threadIdx.x] += lds[threadIdx.x + off];
        __syncthreads();
    }
    if (threadIdx.x == 0) partial[b] = lds[0];
}

// ---------------- final node-axis scan (scan_blocks folded in): rs / deg / dinv ----------------
__global__ __launch_bounds__(256) void scan_final(const unsigned* __restrict__ degp,
                                                  const int* __restrict__ partial,
                                                  int* __restrict__ rs,
                                                  int* __restrict__ deg,
                                                  float* __restrict__ dinv) {
    __shared__ int lds[256];
    int b = blockIdx.x;
    int h = b / 49;
    int tid = threadIdx.x;
    int w = (b % 49) * 256 + tid;
    // block offset = sum of partial[j], j < b  (b < SCAN_B <= 256)
    lds[tid] = (tid < b) ? partial[tid] : 0;
    __syncthreads();
    #pragma unroll
    for (int off = 128; off > 0; off >>= 1) {
        if (tid < off) lds[tid] += lds[tid + off];
        __syncthreads();
    }
    int boff = lds[0];
    __syncthreads();
    unsigned dp = degp[h * WHALF + w];
    int lo = (int)(dp & 0xFFFFu), hi = (int)(dp >> 16);
    int s = lo + hi;
    lds[tid] = s;
    __syncthreads();
    #pragma unroll
    for (int off = 1; off < 256; off <<= 1) {
        int v = lds[tid];
        int add = (tid >= off) ? lds[tid - off] : 0;
        __syncthreads();
        lds[tid] = v + add;
        __syncthreads();
    }
    int excl = boff + lds[tid] - s;
    int n0 = h * HALF_N + 2 * w;
    rs[n0] = excl;
    rs[n0 + 1] = excl + lo;
    deg[n0] = lo;
    deg[n0 + 1] = hi;
    dinv[n0] = (lo > 0) ? (1.0f / (float)lo) : 0.0f;
    dinv[n0 + 1] = (hi > 0) ? (1.0f / (float)hi) : 0.0f;
}

// ---------------- CSR fill: rank via LDS returning atomics; blockIdx.y = half ----------------
// (R7 lesson: global atomic cursors = 50 us of cross-XCD ping-pong; LDS ranks are cheap)
__global__ __launch_bounds__(256) void fill2(const int* __restrict__ src,
                                             const int* __restrict__ dst,
                                             const float* __restrict__ mask,
                                             const unsigned* __restrict__ cnt,
                                             const int* __restrict__ rs,
                                             unsigned* __restrict__ csr) {
    __shared__ unsigned cur[WHALF];   // 50 KB
    int c = blockIdx.x, h = blockIdx.y, tid = threadIdx.x;
    const unsigned* off = cnt + ((size_t)(h * NCHUNK + c)) * WHALF;
    for (int w = tid; w < WHALF; w += 256) cur[w] = off[w];
    __syncthreads();
    int base = c * CE;
    for (int k = tid; k < CE; k += 256) {
        int e = base + k;
        int d = dst[e];
        int local = d - h * HALF_N;
        if (local >= 0 && local < HALF_N) {
            unsigned sm = (unsigned)src[e] | ((unsigned)f2b(mask[e]) << 16);
            int sh = (local & 1) * 16;
            unsigned old = atomicAdd(&cur[local >> 1], 1u << sh);
            int rank = (int)((old >> sh) & 0xFFFFu);
            csr[rs[d] + rank] = sm;
        }
    }
}

// ---------------- gather primitives: issue 16 feature loads / accumulate them ----------------
static __device__ __forceinline__ void issue16(const unsigned short* __restrict__ xb,
                                               unsigned pk, int lane, unsigned* vv) {
    #pragma unroll
    for (int j = 0; j < 16; ++j) {
        unsigned p = (unsigned)__builtin_amdgcn_readlane((int)pk, j);  // 0 for j>=nb
        vv[j] = *(const unsigned*)(xb + (size_t)(p & 0xFFFFu) * DIM + lane * 2);
    }
}
static __device__ __forceinline__ void accum16(unsigned pk, const unsigned* vv,
                                               float& acc0, float& acc1) {
    #pragma unroll
    for (int j = 0; j < 16; ++j) {
        unsigned p = (unsigned)__builtin_amdgcn_readlane((int)pk, j);
        float mm = b2f((unsigned short)(p >> 16));                     // 0 for j>=nb
        acc0 += mm * b2f((unsigned short)(vv[j] & 0xFFFFu));
        acc1 += mm * b2f((unsigned short)(vv[j] >> 16));
    }
}

// ---------------- software-pipelined gather of 4 consecutive nodes into LDS ----------------
// RES32: residual from f32 array (layer 0). Otherwise reconstructed from hi+lo
// bf16 tables (hi read L2-warms the gather table; 2^-18 relative error).
template<bool RES32>
static __device__ __forceinline__ void gather4(const unsigned short* __restrict__ xb,
                                               const float* __restrict__ xres,
                                               const unsigned short* __restrict__ xlo,
                                               const int* __restrict__ rs,
                                               const int* __restrict__ deg,
                                               const float* __restrict__ dinv,
                                               const unsigned* __restrict__ csr,
                                               int nb0, int lane,
                                               float (*ldsrow)[132], int row0) {
    int rs4[4], dg4[4];
    float di4[4];
    #pragma unroll
    for (int i = 0; i < 4; ++i) {
        int n = nb0 + i;
        rs4[i] = rs[n];
        dg4[i] = deg[n];
        di4[i] = dinv[n];
    }
    unsigned pk0, pk1, pk2, pk3;
    pk0 = (lane < (dg4[0] < 16 ? dg4[0] : 16)) ? csr[rs4[0] + lane] : 0u;
    pk1 = (lane < (dg4[1] < 16 ? dg4[1] : 16)) ? csr[rs4[1] + lane] : 0u;

    unsigned vvA[16], vvB[16];
    issue16(xb, pk0, lane, vvA);       // node 0 features in flight

    unsigned pkq[4] = {pk0, pk1, 0u, 0u};
    #pragma unroll
    for (int i = 0; i < 4; ++i) {
        if (i == 0) pk2 = (lane < (dg4[2] < 16 ? dg4[2] : 16)) ? csr[rs4[2] + lane] : 0u;
        if (i == 1) pk3 = (lane < (dg4[3] < 16 ? dg4[3] : 16)) ? csr[rs4[3] + lane] : 0u;
        if (i == 0) pkq[2] = pk2;
        if (i == 1) pkq[3] = pk3;
        if (i < 3) issue16(xb, pkq[i + 1], lane, (i & 1) ? vvA : vvB);  // next node in flight
        float acc0 = 0.f, acc1 = 0.f;
        accum16(pkq[i], (i & 1) ? vvB : vvA, acc0, acc1);
        // extra chunks (deg > 16), serial (rarer path)
        for (int base = 16; base < dg4[i]; base += 16) {
            int nb = dg4[i] - base;
            if (nb > 16) nb = 16;
            unsigned pke = (lane < nb) ? csr[rs4[i] + base + lane] : 0u;
            unsigned vvE[16];
            issue16(xb, pke, lane, vvE);
            accum16(pke, vvE, acc0, acc1);
        }
        float di = di4[i];
        float x0, x1;
        if constexpr (RES32) {
            float2 xp = *(const float2*)(xres + (size_t)(nb0 + i) * DIM + lane * 2);
            x0 = xp.x; x1 = xp.y;
        } else {
            unsigned hv = *(const unsigned*)(xb  + (size_t)(nb0 + i) * DIM + lane * 2);
            unsigned lv = *(const unsigned*)(xlo + (size_t)(nb0 + i) * DIM + lane * 2);
            x0 = b2f((unsigned short)(hv & 0xFFFFu)) + b2f((unsigned short)(lv & 0xFFFFu));
            x1 = b2f((unsigned short)(hv >> 16))     + b2f((unsigned short)(lv >> 16));
        }
        ldsrow[row0 + i][lane * 2]     = x0 + acc0 * di;
        ldsrow[row0 + i][lane * 2 + 1] = x1 + acc1 * di;
    }
}

// ---------------- fused agg + GEMM[N,128]x[128,128] + BN + ReLU ----------------
// 16 rows per block, 4 waves x 4 nodes. Output stored as hi+lo bf16 tables.
template<bool RES32>
__global__ __launch_bounds__(256) void fused_layer(const unsigned short* __restrict__ xb,
                                                   const float* __restrict__ xres,
                                                   const unsigned short* __restrict__ xlo,
                                                   const int* __restrict__ rs,
                                                   const int* __restrict__ deg,
                                                   const float* __restrict__ dinv,
                                                   const unsigned* __restrict__ csr,
                                                   const unsigned short* __restrict__ wfh,
                                                   const unsigned short* __restrict__ wfl,
                                                   const float* __restrict__ bias,
                                                   const float* __restrict__ gam,
                                                   const float* __restrict__ bet,
                                                   const float* __restrict__ rm,
                                                   const float* __restrict__ rv,
                                                   unsigned short* __restrict__ outhi,
                                                   unsigned short* __restrict__ outlo) {
    __shared__ float lds[16][132];   // 8.4 KB
    int tid = threadIdx.x;
    int wave = tid >> 6, lane = tid & 63;
    int rbase = blockIdx.x * 16;     // 3125 * 16 == 50000 exactly

    // ---- phase 1 ----
    gather4<RES32>(xb, xres, xlo, rs, deg, dinv, csr, rbase + wave * 4, lane, lds, wave * 4);
    __syncthreads();   // cross-lane LDS dependency: barrier REQUIRED

    // ---- phase 2: 16x128 GEMM, 2 col-tiles per wave ----
    int m = lane & 15, quad = lane >> 4;
    const float* ap = &lds[m][0];

    us8_t ah[4], al[4];
    #pragma unroll
    for (int kt = 0; kt < 4; ++kt) {
        f32x4_t p0 = *(const f32x4_t*)(ap + kt * 32 + quad * 8);
        f32x4_t p1 = *(const f32x4_t*)(ap + kt * 32 + quad * 8 + 4);
        #pragma unroll
        for (int j = 0; j < 4; ++j) {
            unsigned short h0 = f2b(p0[j]);
            unsigned short h1 = f2b(p1[j]);
            ah[kt][j] = h0;
            ah[kt][4 + j] = h1;
            al[kt][j] = f2b(p0[j] - b2f(h0));
            al[kt][4 + j] = f2b(p1[j] - b2f(h1));
        }
    }

    f32x4_t acc[2] = {};
    #pragma unroll
    for (int kt = 0; kt < 4; ++kt) {
        #pragma unroll
        for (int t = 0; t < 2; ++t) {
            int nt = wave * 2 + t;
            int boff = ((nt * 4 + kt) * 64 + lane) * 8;
            us8_t bh = *(const us8_t*)(wfh + boff);
            us8_t bl = *(const us8_t*)(wfl + boff);
            acc[t] = __builtin_amdgcn_mfma_f32_16x16x32_bf16(
                __builtin_bit_cast(bf16x8_t, ah[kt]),
                __builtin_bit_cast(bf16x8_t, bh), acc[t], 0, 0, 0);
            acc[t] = __builtin_amdgcn_mfma_f32_16x16x32_bf16(
                __builtin_bit_cast(bf16x8_t, ah[kt]),
                __builtin_bit_cast(bf16x8_t, bl), acc[t], 0, 0, 0);
            acc[t] = __builtin_amdgcn_mfma_f32_16x16x32_bf16(
                __builtin_bit_cast(bf16x8_t, al[kt]),
                __builtin_bit_cast(bf16x8_t, bh), acc[t], 0, 0, 0);
        }
    }

    #pragma unroll
    for (int t = 0; t < 2; ++t) {
        int nt = wave * 2 + t;
        int j = nt * 16 + m;
        float bj = bias[j];
        float sc = gam[j] * rsqrtf(rv[j] + 1e-5f);
        float sh = bet[j] - rm[j] * sc;
        #pragma unroll
        for (int i = 0; i < 4; ++i) {
            int r = rbase + quad * 4 + i;
            float z = fmaxf((acc[t][i] + bj) * sc + sh, 0.f);
            unsigned short zh = f2b(z);
            outhi[(size_t)r * DIM + j] = zh;
            outlo[(size_t)r * DIM + j] = f2b(z - b2f(zh));
        }
    }
}

// ---------------- fused final: agg + h3 = relu(BN((h2+agg)@w2+b2)); out = (h2@wp+bp+h3)*0.5 ----------------
// h2 arrives as hi+lo tables: predict-path A-fragments load DIRECTLY as us8.
__global__ __launch_bounds__(256) void fused_final2(const unsigned short* __restrict__ xb,
                                                    const unsigned short* __restrict__ xlo,
                                                    const int* __restrict__ rs,
                                                    const int* __restrict__ deg,
                                                    const float* __restrict__ dinv,
                                                    const unsigned* __restrict__ csr,
                                                    const unsigned short* __restrict__ f2h,
                                                    const unsigned short* __restrict__ f2l,
                                                    const unsigned short* __restrict__ fph,
                                                    const unsigned short* __restrict__ fpl,
                                                    const float* __restrict__ b2,
                                                    const float* __restrict__ g2,
                                                    const float* __restrict__ be2,
                                                    const float* __restrict__ rm2,
                                                    const float* __restrict__ rv2,
                                                    const float* __restrict__ bp,
                                                    float* __restrict__ out) {
    __shared__ float lds[16][132];
    int tid = threadIdx.x;
    int wave = tid >> 6, lane = tid & 63;
    int rbase = blockIdx.x * 16;

    // ---- phase 1: aggregate (h2 + agg) rows into LDS ----
    gather4<false>(xb, nullptr, xlo, rs, deg, dinv, csr, rbase + wave * 4, lane, lds, wave * 4);
    __syncthreads();

    if (wave == 3) return;   // waves 0..2 handle the 3 col-tiles

    // ---- phase 2 ----
    int m = lane & 15, quad = lane >> 4;
    int arow = rbase + m;
    const float* ap2 = &lds[m][0];
    const unsigned short* aphh = xb  + (size_t)arow * DIM;
    const unsigned short* aphl = xlo + (size_t)arow * DIM;

    us8_t a2h[4], a2l[4], ahh[4], ahl[4];
    #pragma unroll
    for (int kt = 0; kt < 4; ++kt) {
        f32x4_t p0 = *(const f32x4_t*)(ap2 + kt * 32 + quad * 8);
        f32x4_t p1 = *(const f32x4_t*)(ap2 + kt * 32 + quad * 8 + 4);
        ahh[kt] = *(const us8_t*)(aphh + kt * 32 + quad * 8);   // direct hi fragment
        ahl[kt] = *(const us8_t*)(aphl + kt * 32 + quad * 8);   // direct lo fragment
        #pragma unroll
        for (int j = 0; j < 4; ++j) {
            unsigned short h0 = f2b(p0[j]), h1 = f2b(p1[j]);
            a2h[kt][j] = h0; a2h[kt][4 + j] = h1;
            a2l[kt][j] = f2b(p0[j] - b2f(h0));
            a2l[kt][4 + j] = f2b(p1[j] - b2f(h1));
        }
    }

    int nt = wave;           // 0..2
    f32x4_t acc2 = {};
    f32x4_t accp = {};
    #pragma unroll
    for (int kt = 0; kt < 4; ++kt) {
        int boff = ((nt * 4 + kt) * 64 + lane) * 8;
        us8_t b2hv = *(const us8_t*)(f2h + boff);
        us8_t b2lv = *(const us8_t*)(f2l + boff);
        us8_t bphv = *(const us8_t*)(fph + boff);
        us8_t bplv = *(const us8_t*)(fpl + boff);
        acc2 = __builtin_amdgcn_mfma_f32_16x16x32_bf16(
            __builtin_bit_cast(bf16x8_t, a2h[kt]),
            __builtin_bit_cast(bf16x8_t, b2hv), acc2, 0, 0, 0);
        acc2 = __builtin_amdgcn_mfma_f32_16x16x32_bf16(
            __builtin_bit_cast(bf16x8_t, a2h[kt]),
            __builtin_bit_cast(bf16x8_t, b2lv), acc2, 0, 0, 0);
        acc2 = __builtin_amdgcn_mfma_f32_16x16x32_bf16(
            __builtin_bit_cast(bf16x8_t, a2l[kt]),
            __builtin_bit_cast(bf16x8_t, b2hv), acc2, 0, 0, 0);
        accp = __builtin_amdgcn_mfma_f32_16x16x32_bf16(
            __builtin_bit_cast(bf16x8_t, ahh[kt]),
            __builtin_bit_cast(bf16x8_t, bphv), accp, 0, 0, 0);
        accp = __builtin_amdgcn_mfma_f32_16x16x32_bf16(
            __builtin_bit_cast(bf16x8_t, ahh[kt]),
            __builtin_bit_cast(bf16x8_t, bplv), accp, 0, 0, 0);
        accp = __builtin_amdgcn_mfma_f32_16x16x32_bf16(
            __builtin_bit_cast(bf16x8_t, ahl[kt]),
            __builtin_bit_cast(bf16x8_t, bphv), accp, 0, 0, 0);
    }

    int j = nt * 16 + m;
    if (j < NCLS) {
        float b2j = b2[j];
        float sc = g2[j] * rsqrtf(rv2[j] + 1e-5f);
        float sh = be2[j] - rm2[j] * sc;
        float bpj = bp[j];
        #pragma unroll
        for (int i = 0; i < 4; ++i) {
            int r = rbase + quad * 4 + i;
            float z = fmaxf((acc2[i] + b2j) * sc + sh, 0.f);
            float p = accp[i] + bpj;
            out[(size_t)r * NCLS + j] = (p + z) * 0.5f;
        }
    }
}

extern "C" void kernel_launch(void* const* d_in, const int* in_sizes, int n_in,
                              void* d_out, int out_size, void* d_ws, size_t ws_size,
                              hipStream_t stream) {
    const float* h    = (const float*)d_in[0];
    const int* esrc   = (const int*)d_in[1];
    const int* edst   = (const int*)d_in[2];
    const float* mask = (const float*)d_in[3];
    const float* w0   = (const float*)d_in[4];
    const float* b0   = (const float*)d_in[5];
    const float* g0   = (const float*)d_in[6];
    const float* be0  = (const float*)d_in[7];
    const float* rm0  = (const float*)d_in[8];
    const float* rv0  = (const float*)d_in[9];
    const float* w1   = (const float*)d_in[10];
    const float* b1   = (const float*)d_in[11];
    const float* g1   = (const float*)d_in[12];
    const float* be1  = (const float*)d_in[13];
    const float* rm1  = (const float*)d_in[14];
    const float* rv1  = (const float*)d_in[15];
    const float* w2   = (const float*)d_in[16];
    const float* b2   = (const float*)d_in[17];
    const float* g2   = (const float*)d_in[18];
    const float* be2  = (const float*)d_in[19];
    const float* rm2  = (const float*)d_in[20];
    const float* rv2  = (const float*)d_in[21];
    const float* wp   = (const float*)d_in[22];
    const float* bp   = (const float*)d_in[23];

    char* ws = (char*)d_ws;
    size_t off = 0;
    auto alloc = [&](size_t bytes) {
        char* p = ws + off;
        off = (off + bytes + 255) & ~(size_t)255;
        return p;
    };
    int* rs       = (int*)alloc(N_PAD * 4);
    int* deg      = (int*)alloc(N_PAD * 4);
    float* dinv   = (float*)alloc(N_PAD * 4);
    int* partial  = (int*)alloc(128 * 4);
    unsigned* degp = (unsigned*)alloc(2 * WHALF * 4);
    unsigned* csr = (unsigned*)alloc((size_t)N_EDGES * 4);
    unsigned* cnt = (unsigned*)alloc((size_t)2 * NCHUNK * WHALF * 4);  // 12.85 MB
    unsigned short* xb16   = (unsigned short*)alloc((size_t)N_NODES * DIM * 2);
    unsigned short* hbA_hi = (unsigned short*)alloc((size_t)N_NODES * DIM * 2);
    unsigned short* hbA_lo = (unsigned short*)alloc((size_t)N_NODES * DIM * 2);
    unsigned short* hbB_hi = (unsigned short*)alloc((size_t)N_NODES * DIM * 2);
    unsigned short* hbB_lo = (unsigned short*)alloc((size_t)N_NODES * DIM * 2);
    unsigned short* f0h = (unsigned short*)alloc(16384 * 2);
    unsigned short* f0l = (unsigned short*)alloc(16384 * 2);
    unsigned short* f1h = (unsigned short*)alloc(16384 * 2);
    unsigned short* f1l = (unsigned short*)alloc(16384 * 2);
    unsigned short* f2h = (unsigned short*)alloc(6144 * 2);
    unsigned short* f2l = (unsigned short*)alloc(6144 * 2);
    unsigned short* fph = (unsigned short*)alloc(6144 * 2);
    unsigned short* fpl = (unsigned short*)alloc(6144 * 2);

    const int GB16 = N_NODES / 16;   // 3125, exact

    prep<<<PREP_B + REPACK_B, 256, 0, stream>>>(h, xb16, w0, w1, w2, wp,
                                                f0h, f0l, f1h, f1l, f2h, f2l, fph, fpl);
    chunk_count<<<dim3(NCHUNK, 2), 256, 0, stream>>>(edst, cnt);
    cscan<<<SCAN_B, 256, 0, stream>>>(cnt, degp, partial);
    scan_final<<<SCAN_B, 256, 0, stream>>>(degp, partial, rs, deg, dinv);
    fill2<<<dim3(NCHUNK, 2), 256, 0, stream>>>(esrc, edst, mask, cnt, rs, csr);

    // layer 0: residual from f32 input h; gather from xb16 -> hbA hi/lo
    fused_layer<true><<<GB16, 256, 0, stream>>>(xb16, h, xb16, rs, deg, dinv, csr,
                                                f0h, f0l, b0, g0, be0, rm0, rv0,
                                                hbA_hi, hbA_lo);
    // layer 1: residual + gather from hbA hi/lo -> hbB hi/lo (double-buffered)
    fused_layer<false><<<GB16, 256, 0, stream>>>(hbA_hi, h, hbA_lo, rs, deg, dinv, csr,
                                                 f1h, f1l, b1, g1, be1, rm1, rv1,
                                                 hbB_hi, hbB_lo);
    // layer 2 + predict, fused: hbB hi/lo -> d_out
    fused_final2<<<GB16, 256, 0, stream>>>(hbB_hi, hbB_lo, rs, deg, dinv, csr,
                                           f2h, f2l, fph, fpl,
                                           b2, g2, be2, rm2, rv2, bp, (float*)d_out);
}

// Round 9
// 286.097 us; speedup vs baseline: 1.8014x; 1.0362x over previous
//
#include <hip/hip_runtime.h>

#define N_NODES 50000
#define N_EDGES 800000
#define DIM 128
#define NCLS 40

// chunked CSR build
#define NCHUNK 128
#define CE 6250            // NCHUNK*CE == N_EDGES exactly
#define HALF_N 25088       // nodes per half (2*WHALF)
#define WHALF 12544        // packed u32 words per half (= 49*256)
#define SCAN_B 98          // scan blocks (2 halves * 49)
#define NSEG 4             // chunk-axis segments (cscan TLP: 392 blocks, 32-iter chains)
#define SEGC 32            // NCHUNK / NSEG
#define N_PAD 50432        // >= 2*HALF_N padded node arrays

typedef __bf16 bf16x8_t __attribute__((ext_vector_type(8)));
typedef unsigned short us8_t __attribute__((ext_vector_type(8)));
typedef float f32x4_t __attribute__((ext_vector_type(4)));

static __device__ __forceinline__ float b2f(unsigned short h) {
    unsigned u = ((unsigned)h) << 16;
    return __builtin_bit_cast(float, u);
}
static __device__ __forceinline__ unsigned short f2b(float f) {
    unsigned u = __builtin_bit_cast(unsigned, f);
    u += 0x7FFFu + ((u >> 16) & 1u);   // RNE; values finite O(1)
    return (unsigned short)(u >> 16);
}

// ---------------- merged prep: f32->bf16 shadow of h + weight repack ----------------
#define PREP_B 3125
#define REPACK_B 176
__global__ __launch_bounds__(256) void prep(const float* __restrict__ hsrc,
                                            unsigned short* __restrict__ hout,
                                            const float* __restrict__ w0,
                                            const float* __restrict__ w1,
                                            const float* __restrict__ w2,
                                            const float* __restrict__ wp,
                                            unsigned short* __restrict__ f0h,
                                            unsigned short* __restrict__ f0l,
                                            unsigned short* __restrict__ f1h,
                                            unsigned short* __restrict__ f1l,
                                            unsigned short* __restrict__ f2h,
                                            unsigned short* __restrict__ f2l,
                                            unsigned short* __restrict__ fph,
                                            unsigned short* __restrict__ fpl) {
    if (blockIdx.x < PREP_B) {
        size_t e0 = ((size_t)blockIdx.x * 256 + threadIdx.x) * 8;
        f32x4_t v0 = *(const f32x4_t*)(hsrc + e0);
        f32x4_t v1 = *(const f32x4_t*)(hsrc + e0 + 4);
        us8_t o;
        #pragma unroll
        for (int j = 0; j < 4; ++j) { o[j] = f2b(v0[j]); o[4 + j] = f2b(v1[j]); }
        *(us8_t*)(hout + e0) = o;
        return;
    }
    int t = (blockIdx.x - PREP_B) * 256 + threadIdx.x;
    const float* src;
    unsigned short *dh, *dl;
    int idx, ncols;
    if (t < 16384)      { src = w0; dh = f0h; dl = f0l; idx = t;         ncols = 128; }
    else if (t < 32768) { src = w1; dh = f1h; dl = f1l; idx = t - 16384; ncols = 128; }
    else if (t < 38912) { src = w2; dh = f2h; dl = f2l; idx = t - 32768; ncols = 48; }
    else if (t < 45056) { src = wp; dh = fph; dl = fpl; idx = t - 38912; ncols = 48; }
    else return;
    int k = idx / ncols, n = idx - k * ncols;
    float v;
    if (ncols == 128) v = src[k * 128 + n];
    else              v = (n < NCLS) ? src[k * NCLS + n] : 0.f;
    int nt = n >> 4, m = n & 15, kt = k >> 5, quad = (k >> 3) & 3, j = k & 7;
    int off = ((nt * 4 + kt) * 64 + quad * 16 + m) * 8 + j;
    unsigned short hi = f2b(v);
    dh[off] = hi;
    dl[off] = f2b(v - b2f(hi));
}

// ---------------- per-chunk per-node edge counts (LDS atomics); blockIdx.y = half ----------------
// block (0,0) also zeroes partial[] (read only by later kernels: no race).
__global__ __launch_bounds__(256) void chunk_count(const int* __restrict__ dst,
                                                   unsigned* __restrict__ cnt,
                                                   int* __restrict__ partial) {
    __shared__ unsigned lds[WHALF];   // 50 KB
    int c = blockIdx.x, h = blockIdx.y, tid = threadIdx.x;
    if (c == 0 && h == 0 && tid < 128) partial[tid] = 0;
    for (int w = tid; w < WHALF; w += 256) lds[w] = 0;
    __syncthreads();
    int base = c * CE;
    for (int k = tid; k < CE; k += 256) {
        int local = dst[base + k] - h * HALF_N;
        if (local >= 0 && local < HALF_N)
            atomicAdd(&lds[local >> 1], 1u << ((local & 1) * 16));
    }
    __syncthreads();
    unsigned* out = cnt + ((size_t)(h * NCHUNK + c)) * WHALF;
    for (int w = tid; w < WHALF; w += 256) out[w] = lds[w];
}

// ---------------- segmented scan over chunk axis: 4x TLP, 32-iter chains ----------------
// cnt[c][w] becomes SEGMENT-local exclusive prefix; per-(seg,w) sums -> segsum;
// per-scan-block totals accumulate into partial via int atomics (deterministic).
__global__ __launch_bounds__(256) void cscan_seg(unsigned* __restrict__ cnt,
                                                 unsigned* __restrict__ segsum,
                                                 int* __restrict__ partial) {
    int bx = blockIdx.x;
    int seg = bx / SCAN_B;
    int b = bx - seg * SCAN_B;
    int h = b / 49;
    int w = (b % 49) * 256 + threadIdx.x;
    unsigned acc = 0;
    int c0 = seg * SEGC;
    for (int c = c0; c < c0 + SEGC; ++c) {
        size_t idx = ((size_t)(h * NCHUNK + c)) * WHALF + w;
        unsigned v = cnt[idx];
        cnt[idx] = acc;          // segment-local exclusive prefix (packed halves)
        acc += v;
    }
    segsum[((size_t)(seg * 2 + h)) * WHALF + w] = acc;
    __shared__ int lds[256];
    lds[threadIdx.x] = (int)(acc & 0xFFFFu) + (int)(acc >> 16);
    __syncthreads();
    #pragma unroll
    for (int off = 128; off > 0; off >>= 1) {
        if (threadIdx.x < off) lds[threadIdx.x] += lds[threadIdx.x + off];
        __syncthreads();
    }
    if (threadIdx.x == 0) atomicAdd(&partial[b], lds[0]);
}

// ---------------- final node-axis scan: seg prefix -> segoff; rs / deg / dinv ----------------
__global__ __launch_bounds__(256) void scan_final(const unsigned* __restrict__ segsum,
                                                  unsigned* __restrict__ segoff,
                                                  const int* __restrict__ partial,
                                                  int* __restrict__ rs,
                                                  int* __restrict__ deg,
                                                  float* __restrict__ dinv) {
    __shared__ int lds[256];
    int b = blockIdx.x;
    int h = b / 49;
    int tid = threadIdx.x;
    int w = (b % 49) * 256 + tid;
    // block offset = sum of partial[j], j < b  (b < SCAN_B <= 128)
    lds[tid] = (tid < b && tid < 128) ? partial[tid] : 0;
    __syncthreads();
    #pragma unroll
    for (int off = 128; off > 0; off >>= 1) {
        if (tid < off) lds[tid] += lds[tid + off];
        __syncthreads();
    }
    int boff = lds[0];
    __syncthreads();
    // segment prefix (packed u16 halves; per-node total < 2^16 so no cross-carry)
    size_t wb = (size_t)h * WHALF + w;
    unsigned run = 0;
    unsigned dp = 0;
    #pragma unroll
    for (int s = 0; s < NSEG; ++s) {
        unsigned sv = segsum[((size_t)(s * 2 + h)) * WHALF + w];
        segoff[((size_t)(s * 2 + h)) * WHALF + w] = run;
        run += sv;
    }
    dp = run;
    int lo = (int)(dp & 0xFFFFu), hi = (int)(dp >> 16);
    int s = lo + hi;
    lds[tid] = s;
    __syncthreads();
    #pragma unroll
    for (int off = 1; off < 256; off <<= 1) {
        int v = lds[tid];
        int add = (tid >= off) ? lds[tid - off] : 0;
        __syncthreads();
        lds[tid] = v + add;
        __syncthreads();
    }
    int excl = boff + lds[tid] - s;
    int n0 = h * HALF_N + 2 * ((b % 49) * 256 + tid);
    (void)wb;
    rs[n0] = excl;
    rs[n0 + 1] = excl + lo;
    deg[n0] = lo;
    deg[n0 + 1] = hi;
    dinv[n0] = (lo > 0) ? (1.0f / (float)lo) : 0.0f;
    dinv[n0 + 1] = (hi > 0) ? (1.0f / (float)hi) : 0.0f;
}

// ---------------- CSR fill: rank via LDS returning atomics; blockIdx.y = half ----------------
// cur init = segment-local cnt + segoff -> identical global-exclusive base as before.
__global__ __launch_bounds__(256) void fill2(const int* __restrict__ src,
                                             const int* __restrict__ dst,
                                             const float* __restrict__ mask,
                                             const unsigned* __restrict__ cnt,
                                             const unsigned* __restrict__ segoff,
                                             const int* __restrict__ rs,
                                             unsigned* __restrict__ csr) {
    __shared__ unsigned cur[WHALF];   // 50 KB
    int c = blockIdx.x, h = blockIdx.y, tid = threadIdx.x;
    int seg = c >> 5;                 // c / SEGC
    const unsigned* off = cnt + ((size_t)(h * NCHUNK + c)) * WHALF;
    const unsigned* soff = segoff + ((size_t)(seg * 2 + h)) * WHALF;
    for (int w = tid; w < WHALF; w += 256) cur[w] = off[w] + soff[w];  // packed add, no carry
    __syncthreads();
    int base = c * CE;
    for (int k = tid; k < CE; k += 256) {
        int e = base + k;
        int d = dst[e];
        int local = d - h * HALF_N;
        if (local >= 0 && local < HALF_N) {
            unsigned sm = (unsigned)src[e] | ((unsigned)f2b(mask[e]) << 16);
            int sh = (local & 1) * 16;
            unsigned old = atomicAdd(&cur[local >> 1], 1u << sh);
            int rank = (int)((old >> sh) & 0xFFFFu);
            csr[rs[d] + rank] = sm;
        }
    }
}

// ---------------- gather primitives ----------------
static __device__ __forceinline__ void issue16(const unsigned short* __restrict__ xb,
                                               unsigned pk, int lane, unsigned* vv) {
    #pragma unroll
    for (int j = 0; j < 16; ++j) {
        unsigned p = (unsigned)__builtin_amdgcn_readlane((int)pk, j);  // 0 for j>=nb
        vv[j] = *(const unsigned*)(xb + (size_t)(p & 0xFFFFu) * DIM + lane * 2);
    }
}
static __device__ __forceinline__ void accum16(unsigned pk, const unsigned* vv,
                                               float& acc0, float& acc1) {
    #pragma unroll
    for (int j = 0; j < 16; ++j) {
        unsigned p = (unsigned)__builtin_amdgcn_readlane((int)pk, j);
        float mm = b2f((unsigned short)(p >> 16));                     // 0 for j>=nb
        acc0 += mm * b2f((unsigned short)(vv[j] & 0xFFFFu));
        acc1 += mm * b2f((unsigned short)(vv[j] >> 16));
    }
}

// ---------------- software-pipelined gather of 4 consecutive nodes into LDS ----------------
template<bool RES32>
static __device__ __forceinline__ void gather4(const unsigned short* __restrict__ xb,
                                               const float* __restrict__ xres,
                                               const unsigned short* __restrict__ xlo,
                                               const int* __restrict__ rs,
                                               const int* __restrict__ deg,
                                               const float* __restrict__ dinv,
                                               const unsigned* __restrict__ csr,
                                               int nb0, int lane,
                                               float (*ldsrow)[132], int row0) {
    int rs4[4], dg4[4];
    float di4[4];
    #pragma unroll
    for (int i = 0; i < 4; ++i) {
        int n = nb0 + i;
        rs4[i] = rs[n];
        dg4[i] = deg[n];
        di4[i] = dinv[n];
    }
    unsigned pk0, pk1, pk2, pk3;
    pk0 = (lane < (dg4[0] < 16 ? dg4[0] : 16)) ? csr[rs4[0] + lane] : 0u;
    pk1 = (lane < (dg4[1] < 16 ? dg4[1] : 16)) ? csr[rs4[1] + lane] : 0u;

    unsigned vvA[16], vvB[16];
    issue16(xb, pk0, lane, vvA);       // node 0 features in flight

    unsigned pkq[4] = {pk0, pk1, 0u, 0u};
    #pragma unroll
    for (int i = 0; i < 4; ++i) {
        if (i == 0) pk2 = (lane < (dg4[2] < 16 ? dg4[2] : 16)) ? csr[rs4[2] + lane] : 0u;
        if (i == 1) pk3 = (lane < (dg4[3] < 16 ? dg4[3] : 16)) ? csr[rs4[3] + lane] : 0u;
        if (i == 0) pkq[2] = pk2;
        if (i == 1) pkq[3] = pk3;
        if (i < 3) issue16(xb, pkq[i + 1], lane, (i & 1) ? vvA : vvB);  // next node in flight
        float acc0 = 0.f, acc1 = 0.f;
        accum16(pkq[i], (i & 1) ? vvB : vvA, acc0, acc1);
        // extra chunks (deg > 16), serial (rarer path)
        for (int base = 16; base < dg4[i]; base += 16) {
            int nb = dg4[i] - base;
            if (nb > 16) nb = 16;
            unsigned pke = (lane < nb) ? csr[rs4[i] + base + lane] : 0u;
            unsigned vvE[16];
            issue16(xb, pke, lane, vvE);
            accum16(pke, vvE, acc0, acc1);
        }
        float di = di4[i];
        float x0, x1;
        if constexpr (RES32) {
            float2 xp = *(const float2*)(xres + (size_t)(nb0 + i) * DIM + lane * 2);
            x0 = xp.x; x1 = xp.y;
        } else {
            unsigned hv = *(const unsigned*)(xb  + (size_t)(nb0 + i) * DIM + lane * 2);
            unsigned lv = *(const unsigned*)(xlo + (size_t)(nb0 + i) * DIM + lane * 2);
            x0 = b2f((unsigned short)(hv & 0xFFFFu)) + b2f((unsigned short)(lv & 0xFFFFu));
            x1 = b2f((unsigned short)(hv >> 16))     + b2f((unsigned short)(lv >> 16));
        }
        ldsrow[row0 + i][lane * 2]     = x0 + acc0 * di;
        ldsrow[row0 + i][lane * 2 + 1] = x1 + acc1 * di;
    }
}

// ---------------- fused agg + GEMM[N,128]x[128,128] + BN + ReLU ----------------
template<bool RES32>
__global__ __launch_bounds__(256) void fused_layer(const unsigned short* __restrict__ xb,
                                                   const float* __restrict__ xres,
                                                   const unsigned short* __restrict__ xlo,
                                                   const int* __restrict__ rs,
                                                   const int* __restrict__ deg,
                                                   const float* __restrict__ dinv,
                                                   const unsigned* __restrict__ csr,
                                                   const unsigned short* __restrict__ wfh,
                                                   const unsigned short* __restrict__ wfl,
                                                   const float* __restrict__ bias,
                                                   const float* __restrict__ gam,
                                                   const float* __restrict__ bet,
                                                   const float* __restrict__ rm,
                                                   const float* __restrict__ rv,
                                                   unsigned short* __restrict__ outhi,
                                                   unsigned short* __restrict__ outlo) {
    __shared__ float lds[16][132];   // 8.4 KB
    int tid = threadIdx.x;
    int wave = tid >> 6, lane = tid & 63;
    int rbase = blockIdx.x * 16;     // 3125 * 16 == 50000 exactly

    gather4<RES32>(xb, xres, xlo, rs, deg, dinv, csr, rbase + wave * 4, lane, lds, wave * 4);
    __syncthreads();   // cross-lane LDS dependency: barrier REQUIRED

    int m = lane & 15, quad = lane >> 4;
    const float* ap = &lds[m][0];

    us8_t ah[4], al[4];
    #pragma unroll
    for (int kt = 0; kt < 4; ++kt) {
        f32x4_t p0 = *(const f32x4_t*)(ap + kt * 32 + quad * 8);
        f32x4_t p1 = *(const f32x4_t*)(ap + kt * 32 + quad * 8 + 4);
        #pragma unroll
        for (int j = 0; j < 4; ++j) {
            unsigned short h0 = f2b(p0[j]);
            unsigned short h1 = f2b(p1[j]);
            ah[kt][j] = h0;
            ah[kt][4 + j] = h1;
            al[kt][j] = f2b(p0[j] - b2f(h0));
            al[kt][4 + j] = f2b(p1[j] - b2f(h1));
        }
    }

    f32x4_t acc[2] = {};
    #pragma unroll
    for (int kt = 0; kt < 4; ++kt) {
        #pragma unroll
        for (int t = 0; t < 2; ++t) {
            int nt = wave * 2 + t;
            int boff = ((nt * 4 + kt) * 64 + lane) * 8;
            us8_t bh = *(const us8_t*)(wfh + boff);
            us8_t bl = *(const us8_t*)(wfl + boff);
            acc[t] = __builtin_amdgcn_mfma_f32_16x16x32_bf16(
                __builtin_bit_cast(bf16x8_t, ah[kt]),
                __builtin_bit_cast(bf16x8_t, bh), acc[t], 0, 0, 0);
            acc[t] = __builtin_amdgcn_mfma_f32_16x16x32_bf16(
                __builtin_bit_cast(bf16x8_t, ah[kt]),
                __builtin_bit_cast(bf16x8_t, bl), acc[t], 0, 0, 0);
            acc[t] = __builtin_amdgcn_mfma_f32_16x16x32_bf16(
                __builtin_bit_cast(bf16x8_t, al[kt]),
                __builtin_bit_cast(bf16x8_t, bh), acc[t], 0, 0, 0);
        }
    }

    #pragma unroll
    for (int t = 0; t < 2; ++t) {
        int nt = wave * 2 + t;
        int j = nt * 16 + m;
        float bj = bias[j];
        float sc = gam[j] * rsqrtf(rv[j] + 1e-5f);
        float sh = bet[j] - rm[j] * sc;
        #pragma unroll
        for (int i = 0; i < 4; ++i) {
            int r = rbase + quad * 4 + i;
            float z = fmaxf((acc[t][i] + bj) * sc + sh, 0.f);
            unsigned short zh = f2b(z);
            outhi[(size_t)r * DIM + j] = zh;
            outlo[(size_t)r * DIM + j] = f2b(z - b2f(zh));
        }
    }
}

// ---------------- fused final ----------------
__global__ __launch_bounds__(256) void fused_final2(const unsigned short* __restrict__ xb,
                                                    const unsigned short* __restrict__ xlo,
                                                    const int* __restrict__ rs,
                                                    const int* __restrict__ deg,
                                                    const float* __restrict__ dinv,
                                                    const unsigned* __restrict__ csr,
                                                    const unsigned short* __restrict__ f2h,
                                                    const unsigned short* __restrict__ f2l,
                                                    const unsigned short* __restrict__ fph,
                                                    const unsigned short* __restrict__ fpl,
                                                    const float* __restrict__ b2,
                                                    const float* __restrict__ g2,
                                                    const float* __restrict__ be2,
                                                    const float* __restrict__ rm2,
                                                    const float* __restrict__ rv2,
                                                    const float* __restrict__ bp,
                                                    float* __restrict__ out) {
    __shared__ float lds[16][132];
    int tid = threadIdx.x;
    int wave = tid >> 6, lane = tid & 63;
    int rbase = blockIdx.x * 16;

    gather4<false>(xb, nullptr, xlo, rs, deg, dinv, csr, rbase + wave * 4, lane, lds, wave * 4);
    __syncthreads();

    if (wave == 3) return;   // waves 0..2 handle the 3 col-tiles

    int m = lane & 15, quad = lane >> 4;
    int arow = rbase + m;
    const float* ap2 = &lds[m][0];
    const unsigned short* aphh = xb  + (size_t)arow * DIM;
    const unsigned short* aphl = xlo + (size_t)arow * DIM;

    us8_t a2h[4], a2l[4], ahh[4], ahl[4];
    #pragma unroll
    for (int kt = 0; kt < 4; ++kt) {
        f32x4_t p0 = *(const f32x4_t*)(ap2 + kt * 32 + quad * 8);
        f32x4_t p1 = *(const f32x4_t*)(ap2 + kt * 32 + quad * 8 + 4);
        ahh[kt] = *(const us8_t*)(aphh + kt * 32 + quad * 8);   // direct hi fragment
        ahl[kt] = *(const us8_t*)(aphl + kt * 32 + quad * 8);   // direct lo fragment
        #pragma unroll
        for (int j = 0; j < 4; ++j) {
            unsigned short h0 = f2b(p0[j]), h1 = f2b(p1[j]);
            a2h[kt][j] = h0; a2h[kt][4 + j] = h1;
            a2l[kt][j] = f2b(p0[j] - b2f(h0));
            a2l[kt][4 + j] = f2b(p1[j] - b2f(h1));
        }
    }

    int nt = wave;           // 0..2
    f32x4_t acc2 = {};
    f32x4_t accp = {};
    #pragma unroll
    for (int kt = 0; kt < 4; ++kt) {
        int boff = ((nt * 4 + kt) * 64 + lane) * 8;
        us8_t b2hv = *(const us8_t*)(f2h + boff);
        us8_t b2lv = *(const us8_t*)(f2l + boff);
        us8_t bphv = *(const us8_t*)(fph + boff);
        us8_t bplv = *(const us8_t*)(fpl + boff);
        acc2 = __builtin_amdgcn_mfma_f32_16x16x32_bf16(
            __builtin_bit_cast(bf16x8_t, a2h[kt]),
            __builtin_bit_cast(bf16x8_t, b2hv), acc2, 0, 0, 0);
        acc2 = __builtin_amdgcn_mfma_f32_16x16x32_bf16(
            __builtin_bit_cast(bf16x8_t, a2h[kt]),
            __builtin_bit_cast(bf16x8_t, b2lv), acc2, 0, 0, 0);
        acc2 = __builtin_amdgcn_mfma_f32_16x16x32_bf16(
            __builtin_bit_cast(bf16x8_t, a2l[kt]),
            __builtin_bit_cast(bf16x8_t, b2hv), acc2, 0, 0, 0);
        accp = __builtin_amdgcn_mfma_f32_16x16x32_bf16(
            __builtin_bit_cast(bf16x8_t, ahh[kt]),
            __builtin_bit_cast(bf16x8_t, bphv), accp, 0, 0, 0);
        accp = __builtin_amdgcn_mfma_f32_16x16x32_bf16(
            __builtin_bit_cast(bf16x8_t, ahh[kt]),
            __builtin_bit_cast(bf16x8_t, bplv), accp, 0, 0, 0);
        accp = __builtin_amdgcn_mfma_f32_16x16x32_bf16(
            __builtin_bit_cast(bf16x8_t, ahl[kt]),
            __builtin_bit_cast(bf16x8_t, bphv), accp, 0, 0, 0);
    }

    int j = nt * 16 + m;
    if (j < NCLS) {
        float b2j = b2[j];
        float sc = g2[j] * rsqrtf(rv2[j] + 1e-5f);
        float sh = be2[j] - rm2[j] * sc;
        float bpj = bp[j];
        #pragma unroll
        for (int i = 0; i < 4; ++i) {
            int r = rbase + quad * 4 + i;
            float z = fmaxf((acc2[i] + b2j) * sc + sh, 0.f);
            float p = accp[i] + bpj;
            out[(size_t)r * NCLS + j] = (p + z) * 0.5f;
        }
    }
}

extern "C" void kernel_launch(void* const* d_in, const int* in_sizes, int n_in,
                              void* d_out, int out_size, void* d_ws, size_t ws_size,
                              hipStream_t stream) {
    const float* h    = (const float*)d_in[0];
    const int* esrc   = (const int*)d_in[1];
    const int* edst   = (const int*)d_in[2];
    const float* mask = (const float*)d_in[3];
    const float* w0   = (const float*)d_in[4];
    const float* b0   = (const float*)d_in[5];
    const float* g0   = (const float*)d_in[6];
    const float* be0  = (const float*)d_in[7];
    const float* rm0  = (const float*)d_in[8];
    const float* rv0  = (const float*)d_in[9];
    const float* w1   = (const float*)d_in[10];
    const float* b1   = (const float*)d_in[11];
    const float* g1   = (const float*)d_in[12];
    const float* be1  = (const float*)d_in[13];
    const float* rm1  = (const float*)d_in[14];
    const float* rv1  = (const float*)d_in[15];
    const float* w2   = (const float*)d_in[16];
    const float* b2   = (const float*)d_in[17];
    const float* g2   = (const float*)d_in[18];
    const float* be2  = (const float*)d_in[19];
    const float* rm2  = (const float*)d_in[20];
    const float* rv2  = (const float*)d_in[21];
    const float* wp   = (const float*)d_in[22];
    const float* bp   = (const float*)d_in[23];

    char* ws = (char*)d_ws;
    size_t off = 0;
    auto alloc = [&](size_t bytes) {
        char* p = ws + off;
        off = (off + bytes + 255) & ~(size_t)255;
        return p;
    };
    int* rs       = (int*)alloc(N_PAD * 4);
    int* deg      = (int*)alloc(N_PAD * 4);
    float* dinv   = (float*)alloc(N_PAD * 4);
    int* partial  = (int*)alloc(128 * 4);
    unsigned* segsum = (unsigned*)alloc((size_t)NSEG * 2 * WHALF * 4);
    unsigned* segoff = (unsigned*)alloc((size_t)NSEG * 2 * WHALF * 4);
    unsigned* csr = (unsigned*)alloc((size_t)N_EDGES * 4);
    unsigned* cnt = (unsigned*)alloc((size_t)2 * NCHUNK * WHALF * 4);  // 12.85 MB
    unsigned short* xb16   = (unsigned short*)alloc((size_t)N_NODES * DIM * 2);
    unsigned short* hbA_hi = (unsigned short*)alloc((size_t)N_NODES * DIM * 2);
    unsigned short* hbA_lo = (unsigned short*)alloc((size_t)N_NODES * DIM * 2);
    unsigned short* hbB_hi = (unsigned short*)alloc((size_t)N_NODES * DIM * 2);
    unsigned short* hbB_lo = (unsigned short*)alloc((size_t)N_NODES * DIM * 2);
    unsigned short* f0h = (unsigned short*)alloc(16384 * 2);
    unsigned short* f0l = (unsigned short*)alloc(16384 * 2);
    unsigned short* f1h = (unsigned short*)alloc(16384 * 2);
    unsigned short* f1l = (unsigned short*)alloc(16384 * 2);
    unsigned short* f2h = (unsigned short*)alloc(6144 * 2);
    unsigned short* f2l = (unsigned short*)alloc(6144 * 2);
    unsigned short* fph = (unsigned short*)alloc(6144 * 2);
    unsigned short* fpl = (unsigned short*)alloc(6144 * 2);

    const int GB16 = N_NODES / 16;   // 3125, exact

    prep<<<PREP_B + REPACK_B, 256, 0, stream>>>(h, xb16, w0, w1, w2, wp,
                                                f0h, f0l, f1h, f1l, f2h, f2l, fph, fpl);
    chunk_count<<<dim3(NCHUNK, 2), 256, 0, stream>>>(edst, cnt, partial);
    cscan_seg<<<SCAN_B * NSEG, 256, 0, stream>>>(cnt, segsum, partial);
    scan_final<<<SCAN_B, 256, 0, stream>>>(segsum, segoff, partial, rs, deg, dinv);
    fill2<<<dim3(NCHUNK, 2), 256, 0, stream>>>(esrc, edst, mask, cnt, segoff, rs, csr);

    // layer 0: residual from f32 input h; gather from xb16 -> hbA hi/lo
    fused_layer<true><<<GB16, 256, 0, stream>>>(xb16, h, xb16, rs, deg, dinv, csr,
                                                f0h, f0l, b0, g0, be0, rm0, rv0,
                                                hbA_hi, hbA_lo);
    // layer 1: residual + gather from hbA hi/lo -> hbB hi/lo (double-buffered)
    fused_layer<false><<<GB16, 256, 0, stream>>>(hbA_hi, h, hbA_lo, rs, deg, dinv, csr,
                                                 f1h, f1l, b1, g1, be1, rm1, rv1,
                                                 hbB_hi, hbB_lo);
    // layer 2 + predict, fused: hbB hi/lo -> d_out
    fused_final2<<<GB16, 256, 0, stream>>>(hbB_hi, hbB_lo, rs, deg, dinv, csr,
                                           f2h, f2l, fph, fpl,
                                           b2, g2, be2, rm2, rv2, bp, (float*)d_out);
}